// Round 10
// baseline (187.926 us; speedup 1.0000x reference)
//
#include <hip/hip_runtime.h>
#include <hip/hip_bf16.h>

#define NVOX 4096
#define C    128
#define HID  512
#define EPSF 1e-6f

typedef __attribute__((ext_vector_type(8))) short bf16x8;
typedef __attribute__((ext_vector_type(4))) float f32x4;

__device__ __forceinline__ short f2bs(float f) {
    __hip_bfloat16 h = __float2bfloat16(f);
    short s; __builtin_memcpy(&s, &h, 2); return s;
}
__device__ __forceinline__ float bs2f(unsigned short u) {
    return __uint_as_float(((unsigned)u) << 16);
}

__device__ __forceinline__ bf16x8 lda(const short* hs, int lane, int ks) {
    int r = lane & 15, g = lane >> 4;
    int col = (ks * 32 + g * 8) ^ ((r & 7) << 3);
    return *(const bf16x8*)(hs + r * 128 + col);
}

__device__ __forceinline__ float wave_rsum(float s) {
    s += __shfl_xor(s, 32); s += __shfl_xor(s, 16); s += __shfl_xor(s, 8);
    s += __shfl_xor(s, 4);  s += __shfl_xor(s, 2);  s += __shfl_xor(s, 1);
    return s;
}

// device-wide barrier: monotonic counter (zeroed per call via hipMemsetAsync).
// All 256 blocks are guaranteed co-resident (62KB LDS, 256 thr -> >=2 blocks/CU capacity).
__device__ __forceinline__ void gbar(unsigned* cnt, unsigned target) {
    __syncthreads();
    __threadfence();                 // release: push this block's stores to coherent point
    if (threadIdx.x == 0) {
        __hip_atomic_fetch_add(cnt, 1u, __ATOMIC_ACQ_REL, __HIP_MEMORY_SCOPE_AGENT);
        while (__hip_atomic_load(cnt, __ATOMIC_ACQUIRE, __HIP_MEMORY_SCOPE_AGENT) < target)
            __builtin_amdgcn_s_sleep(1);
    }
    __syncthreads();
    __threadfence();                 // acquire: invalidate stale L1/L2 lines
    __syncthreads();
}

// ---------------- persistent mega-kernel: prep | qkv | attn | post ----------------
__global__ void __launch_bounds__(256) k_mega(
    const float* __restrict__ x,  const float* __restrict__ n1,
    const float* __restrict__ anw, const float* __restrict__ n2w,
    const float* __restrict__ wq, const float* __restrict__ wk,
    const float* __restrict__ wv, const float* __restrict__ wo,
    const float* __restrict__ gw, const float* __restrict__ uw,
    const float* __restrict__ dw, float* __restrict__ out,
    short* __restrict__ qbf, short* __restrict__ kbf,
    short* __restrict__ vbf, short* __restrict__ obf,
    short* __restrict__ wsw, unsigned* __restrict__ bar)
{
    __shared__ __align__(16) char smem[61952];
    __shared__ int tab[125];
    const int t = threadIdx.x;
    const int bid = blockIdx.x;
    const int w = t >> 6, lane = t & 63;

    // ========== phase 0: weight prep (fp32 -> bf16 fragment order), 128 thr/block ==========
    if (t < 128) {
        int id = bid * 128 + t;            // [0, 32768)
        const float* src; int base, ct, ks, ln, N, KS;
        if (id < 8192) {                   // wq/wk/wv/wo: 128x128
            int m = id >> 11, loc = id & 2047;
            src = (m == 0) ? wq : (m == 1) ? wk : (m == 2) ? wv : wo;
            base = m << 14; N = 128; KS = 4;
            ct = loc >> 8; ks = (loc >> 6) & 3; ln = loc & 63;
        } else if (id < 16384) {           // gw: 128x512
            int loc = id - 8192;
            src = gw; base = 65536; N = 512; KS = 4;
            ct = loc >> 8; ks = (loc >> 6) & 3; ln = loc & 63;
        } else if (id < 24576) {           // uw: 128x512
            int loc = id - 16384;
            src = uw; base = 131072; N = 512; KS = 4;
            ct = loc >> 8; ks = (loc >> 6) & 3; ln = loc & 63;
        } else {                           // dw: 512x128
            int loc = id - 24576;
            src = dw; base = 196608; N = 128; KS = 16;
            ct = loc >> 10; ks = (loc >> 6) & 15; ln = loc & 63;
        }
        int k0 = ks * 32 + (ln >> 4) * 8;
        int c  = ct * 16 + (ln & 15);
        bf16x8 v;
        #pragma unroll
        for (int j = 0; j < 8; j++) v[j] = f2bs(src[(size_t)(k0 + j) * N + c]);
        *(bf16x8*)(wsw + base + (((ct * KS + ks) * 64 + ln) << 3)) = v;
    }
    gbar(bar, 256);

    // ========== phase 1: rmsnorm(x)*n1 -> q,k,v (bf16) ==========
    {
        short* hs = (short*)smem;
        const int r0 = bid * 16;
        #pragma unroll
        for (int i = 0; i < 4; i++) {
            int r = w * 4 + i;
            const float* xp = x + (size_t)(r0 + r) * 128;
            float v0 = xp[lane], v1 = xp[lane + 64];
            float s = wave_rsum(fmaf(v0, v0, v1 * v1));
            float sc = rsqrtf(s * (1.0f / 128.0f) + EPSF);
            int p3 = (r & 7) << 3;
            hs[r * 128 + (lane ^ p3)]        = f2bs(v0 * sc * n1[lane]);
            hs[r * 128 + ((lane + 64) ^ p3)] = f2bs(v1 * sc * n1[lane + 64]);
        }
        __syncthreads();

        bf16x8 af[4];
        #pragma unroll
        for (int ks = 0; ks < 4; ks++) af[ks] = lda(hs, lane, ks);

        const int rb = (lane >> 4) * 4, cl = lane & 15, cb = w * 32;
        #pragma unroll
        for (int m = 0; m < 3; m++) {
            const short* wb = wsw + (m << 14);
            f32x4 a0 = {0.f,0.f,0.f,0.f}, a1 = {0.f,0.f,0.f,0.f};
            #pragma unroll
            for (int ks = 0; ks < 4; ks++) {
                bf16x8 b0 = *(const bf16x8*)(wb + ((((w * 2) * 4 + ks) * 64 + lane) << 3));
                bf16x8 b1 = *(const bf16x8*)(wb + ((((w * 2 + 1) * 4 + ks) * 64 + lane) << 3));
                a0 = __builtin_amdgcn_mfma_f32_16x16x32_bf16(af[ks], b0, a0, 0, 0, 0);
                a1 = __builtin_amdgcn_mfma_f32_16x16x32_bf16(af[ks], b1, a1, 0, 0, 0);
            }
            short* outp = (m == 0) ? qbf : (m == 1) ? kbf : vbf;
            #pragma unroll
            for (int i = 0; i < 4; i++) {
                outp[(size_t)(r0 + rb + i) * 128 + cb + cl]      = f2bs(a0[i]);
                outp[(size_t)(r0 + rb + i) * 128 + cb + 16 + cl] = f2bs(a1[i]);
            }
        }
    }
    gbar(bar, 512);

    // ========== phase 2: brick attention, 2 (brick,head) units sequentially ==========
    {
        short* K_lds = (short*)smem;            // 30720 B
        short* V_lds = (short*)(smem + 30720);  // 30720 B
        const int b = bid >> 1;
        const int ow = (b & 3) * 4, oh = ((b >> 2) & 3) * 4, od = (b >> 4) * 2;

        if (t < 125) {
            int dd = t / 25, rem = t % 25;
            tab[t] = dd | ((rem / 5) << 4) | ((rem % 5) << 8);
        }

        #pragma unroll
        for (int ui = 0; ui < 2; ui++) {
            const int head = ((bid & 1) << 1) | ui;

            for (int row = t; row < 384; row += 256) {
                int lw = row & 7, lh = (row >> 3) & 7, ld = row >> 6;
                int gd = od - 2 + ld, gh = oh - 2 + lh, gw_ = ow - 2 + lw;
                uint4 kc[4], vc[4];
                if (((unsigned)gd < 16u) && ((unsigned)gh < 16u) && ((unsigned)gw_ < 16u)) {
                    size_t off = ((size_t)(((gd << 4) | gh) << 4 | gw_)) * 128 + head * 32;
                    #pragma unroll
                    for (int c2 = 0; c2 < 4; c2++) {
                        kc[c2] = *(const uint4*)(kbf + off + c2 * 8);
                        vc[c2] = *(const uint4*)(vbf + off + c2 * 8);
                    }
                } else {
                    #pragma unroll
                    for (int c2 = 0; c2 < 4; c2++) { kc[c2] = (uint4){0,0,0,0}; vc[c2] = (uint4){0,0,0,0}; }
                }
                #pragma unroll
                for (int c2 = 0; c2 < 4; c2++) {
                    *(uint4*)&K_lds[row * 40 + c2 * 8] = kc[c2];
                    *(uint4*)&V_lds[row * 40 + c2 * 8] = vc[c2];
                }
            }
            __syncthreads();

            const int qi = t >> 3, qt = t & 7;
            const int qw_ = qi & 3, qh_ = (qi >> 2) & 3, qd_ = qi >> 4;
            const int gqd = od + qd_, gqh = oh + qh_, gqw = ow + qw_;
            const int gvox = (((gqd << 4) | gqh) << 4) | gqw;
            const int base = (qd_ + 2) * 64 + (qh_ + 2) * 8 + (qw_ + 2);

            float qreg[32];
            {
                const float isq = 0.17677669529663687f;
                const short* qp = qbf + (size_t)gvox * 128 + head * 32;
                #pragma unroll
                for (int c2 = 0; c2 < 4; c2++) {
                    uint4 raw = *(const uint4*)(qp + c2 * 8);
                    const unsigned short* u = (const unsigned short*)&raw;
                    #pragma unroll
                    for (int j = 0; j < 8; j++) qreg[c2 * 8 + j] = bs2f(u[j]) * isq;
                }
            }

            float sc[16]; int hid[16];
            float m = -1e30f;
            const int kk0 = qt * 16;
            #pragma unroll
            for (int i = 0; i < 16; i++) {
                int kk = kk0 + i;
                float s = -1e30f; int h = 0;
                if (kk < 125) {
                    int tt = tab[kk];
                    int dd = (tt & 15) - 2, dh = ((tt >> 4) & 15) - 2, dw_ = (tt >> 8) - 2;
                    if (((unsigned)(gqd + dd) < 16u) & ((unsigned)(gqh + dh) < 16u) & ((unsigned)(gqw + dw_) < 16u)) {
                        h = base + dd * 64 + dh * 8 + dw_;
                        float acc = 0.f;
                        #pragma unroll
                        for (int c2 = 0; c2 < 4; c2++) {
                            uint4 raw = *(const uint4*)&K_lds[h * 40 + c2 * 8];
                            const unsigned short* u = (const unsigned short*)&raw;
                            #pragma unroll
                            for (int j = 0; j < 8; j++) acc = fmaf(qreg[c2 * 8 + j], bs2f(u[j]), acc);
                        }
                        s = acc;
                    }
                }
                sc[i] = s; hid[i] = h;
                m = fmaxf(m, s);
            }
            m = fmaxf(m, __shfl_xor(m, 1));
            m = fmaxf(m, __shfl_xor(m, 2));
            m = fmaxf(m, __shfl_xor(m, 4));
            float ssum = 0.f;
            #pragma unroll
            for (int i = 0; i < 16; i++) {
                float p = (sc[i] > -1e29f) ? __expf(sc[i] - m) : 0.f;
                sc[i] = p; ssum += p;
            }
            ssum += __shfl_xor(ssum, 1);
            ssum += __shfl_xor(ssum, 2);
            ssum += __shfl_xor(ssum, 4);
            const float inv = 1.0f / ssum;

            float acc[32];
            #pragma unroll
            for (int c2 = 0; c2 < 32; c2++) acc[c2] = 0.f;
            #pragma unroll
            for (int i = 0; i < 16; i++) {
                float p = sc[i]; int h = hid[i];
                #pragma unroll
                for (int c2 = 0; c2 < 4; c2++) {
                    uint4 raw = *(const uint4*)&V_lds[h * 40 + c2 * 8];
                    const unsigned short* u = (const unsigned short*)&raw;
                    #pragma unroll
                    for (int j = 0; j < 8; j++) acc[c2 * 8 + j] = fmaf(p, bs2f(u[j]), acc[c2 * 8 + j]);
                }
            }
            #pragma unroll
            for (int c2 = 0; c2 < 32; c2++) {
                acc[c2] += __shfl_xor(acc[c2], 1);
                acc[c2] += __shfl_xor(acc[c2], 2);
                acc[c2] += __shfl_xor(acc[c2], 4);
            }
            short o4[4];
            #pragma unroll
            for (int j = 0; j < 4; j++) o4[j] = f2bs(acc[qt * 4 + j] * inv);
            unsigned long long pk; __builtin_memcpy(&pk, o4, 8);
            *(unsigned long long*)&obf[(size_t)gvox * 128 + head * 32 + qt * 4] = pk;
            __syncthreads();
        }
    }
    gbar(bar, 768);

    // ========== phase 3: attnout + ffn1 + ffn2 (LDS-resident) ==========
    {
        float (*ybuf)[132] = (float(*)[132])smem;                // 8448
        float (*xres)[128] = (float(*)[128])(smem + 8448);       // 8192
        short* hs          = (short*)(smem + 16640);             // 4096
        short* gu          = (short*)(smem + 20736);             // 16384
        const int r0 = bid * 16;
        const int ar = lane & 15, ag_ = lane >> 4;

        // y = o @ wo
        {
            const short* wb = wsw + (3 << 14);
            f32x4 a0 = {0.f,0.f,0.f,0.f}, a1 = {0.f,0.f,0.f,0.f};
            #pragma unroll
            for (int ks = 0; ks < 4; ks++) {
                bf16x8 a = *(const bf16x8*)(obf + (size_t)(r0 + ar) * 128 + ks * 32 + ag_ * 8);
                bf16x8 b0 = *(const bf16x8*)(wb + ((((w * 2) * 4 + ks) * 64 + lane) << 3));
                bf16x8 b1 = *(const bf16x8*)(wb + ((((w * 2 + 1) * 4 + ks) * 64 + lane) << 3));
                a0 = __builtin_amdgcn_mfma_f32_16x16x32_bf16(a, b0, a0, 0, 0, 0);
                a1 = __builtin_amdgcn_mfma_f32_16x16x32_bf16(a, b1, a1, 0, 0, 0);
            }
            #pragma unroll
            for (int i = 0; i < 4; i++) {
                ybuf[ag_ * 4 + i][w * 32 + ar]      = a0[i];
                ybuf[ag_ * 4 + i][w * 32 + 16 + ar] = a1[i];
            }
        }
        __syncthreads();

        // per-wave: xres = x + rmsnorm(y)*anw; hs = rmsnorm(xres)*n2w (swizzled bf16)
        #pragma unroll
        for (int i = 0; i < 4; i++) {
            int r = w * 4 + i;
            float y0 = ybuf[r][lane], y1 = ybuf[r][lane + 64];
            float s = wave_rsum(fmaf(y0, y0, y1 * y1));
            float sc = rsqrtf(s * (1.0f / 128.0f) + EPSF);
            const float* xp = x + (size_t)(r0 + r) * 128;
            float xr0 = xp[lane]      + y0 * sc * anw[lane];
            float xr1 = xp[lane + 64] + y1 * sc * anw[lane + 64];
            xres[r][lane] = xr0; xres[r][lane + 64] = xr1;
            float s2 = wave_rsum(fmaf(xr0, xr0, xr1 * xr1));
            float sc2 = rsqrtf(s2 * (1.0f / 128.0f) + EPSF);
            int p3 = (r & 7) << 3;
            hs[r * 128 + (lane ^ p3)]        = f2bs(xr0 * sc2 * n2w[lane]);
            hs[r * 128 + ((lane + 64) ^ p3)] = f2bs(xr1 * sc2 * n2w[lane + 64]);
        }
        __syncthreads();

        // gu = silu(h2@gw)*(h2@uw)
        {
            const short* gwb = wsw + 65536;
            const short* uwb = wsw + 131072;
            bf16x8 af[4];
            #pragma unroll
            for (int ks = 0; ks < 4; ks++) af[ks] = lda(hs, lane, ks);
            f32x4 ag[8], au[8];
            #pragma unroll
            for (int i = 0; i < 8; i++) { ag[i] = (f32x4){0.f,0.f,0.f,0.f}; au[i] = (f32x4){0.f,0.f,0.f,0.f}; }
            #pragma unroll
            for (int ks = 0; ks < 4; ks++) {
                #pragma unroll
                for (int i = 0; i < 8; i++) {
                    int ct = w * 8 + i;
                    bf16x8 bg = *(const bf16x8*)(gwb + (((ct * 4 + ks) * 64 + lane) << 3));
                    bf16x8 bu = *(const bf16x8*)(uwb + (((ct * 4 + ks) * 64 + lane) << 3));
                    ag[i] = __builtin_amdgcn_mfma_f32_16x16x32_bf16(af[ks], bg, ag[i], 0, 0, 0);
                    au[i] = __builtin_amdgcn_mfma_f32_16x16x32_bf16(af[ks], bu, au[i], 0, 0, 0);
                }
            }
            #pragma unroll
            for (int i = 0; i < 8; i++) {
                int col = (w * 8 + i) * 16 + ar;
                #pragma unroll
                for (int j = 0; j < 4; j++) {
                    int row = ag_ * 4 + j;
                    float g = ag[i][j], uu = au[i][j];
                    float sg = g / (1.0f + __expf(-g));
                    gu[row * 512 + (col ^ ((row & 7) << 3))] = f2bs(sg * uu);
                }
            }
        }
        __syncthreads();

        // out = xres + gu @ dw
        {
            const short* db = wsw + 196608;
            f32x4 a0 = {0.f,0.f,0.f,0.f}, a1 = {0.f,0.f,0.f,0.f};
            #pragma unroll
            for (int ks = 0; ks < 16; ks++) {
                int col = (ks * 32 + ag_ * 8) ^ ((ar & 7) << 3);
                bf16x8 a = *(const bf16x8*)(gu + ar * 512 + col);
                bf16x8 b0 = *(const bf16x8*)(db + ((((w * 2) * 16 + ks) * 64 + lane) << 3));
                bf16x8 b1 = *(const bf16x8*)(db + ((((w * 2 + 1) * 16 + ks) * 64 + lane) << 3));
                a0 = __builtin_amdgcn_mfma_f32_16x16x32_bf16(a, b0, a0, 0, 0, 0);
                a1 = __builtin_amdgcn_mfma_f32_16x16x32_bf16(a, b1, a1, 0, 0, 0);
            }
            #pragma unroll
            for (int i = 0; i < 4; i++) {
                int row = ag_ * 4 + i;
                size_t i0 = (size_t)(r0 + row) * 128 + w * 32 + ar;
                out[i0]      = xres[row][w * 32 + ar]      + a0[i];
                out[i0 + 16] = xres[row][w * 32 + 16 + ar] + a1[i];
            }
        }
    }
}

extern "C" void kernel_launch(void* const* d_in, const int* in_sizes, int n_in,
                              void* d_out, int out_size, void* d_ws, size_t ws_size,
                              hipStream_t stream)
{
    const float* x   = (const float*)d_in[0];
    const float* n1  = (const float*)d_in[1];
    const float* anw = (const float*)d_in[2];
    const float* n2  = (const float*)d_in[3];
    const float* wq  = (const float*)d_in[4];
    const float* wk  = (const float*)d_in[5];
    const float* wv  = (const float*)d_in[6];
    const float* wo  = (const float*)d_in[7];
    const float* gw  = (const float*)d_in[8];
    const float* uw  = (const float*)d_in[9];
    const float* dw  = (const float*)d_in[10];
    float* out = (float*)d_out;

    float* ws = (float*)d_ws;
    short* qbf = (short*)ws;                   // 524288 shorts
    short* kbf = (short*)(ws + 262144);
    short* vbf = (short*)(ws + 524288);
    short* obf = (short*)(ws + 786432);
    short* wsw = (short*)(ws + 1048576);       // 262144 shorts
    unsigned* bar = (unsigned*)(ws + 1179648); // barrier counter (zeroed each call)

    hipMemsetAsync(bar, 0, 128, stream);
    k_mega<<<256, 256, 0, stream>>>(x, n1, anw, n2, wq, wk, wv, wo, gw, uw, dw,
                                    out, qbf, kbf, vbf, obf, wsw, bar);
}

// Round 11
// 51.224 us; speedup vs baseline: 3.6687x; 3.6687x over previous
//
#include <hip/hip_runtime.h>
#include <hip/hip_bf16.h>
#include <hip/hip_fp16.h>

#define NVOX 4096
#define C    128
#define HID  512
#define EPSF 1e-6f

typedef __attribute__((ext_vector_type(8))) short bf16x8;
typedef __attribute__((ext_vector_type(4))) float f32x4;

__device__ __forceinline__ short f2bs(float f) {
    __hip_bfloat16 h = __float2bfloat16(f);
    short s; __builtin_memcpy(&s, &h, 2); return s;
}
__device__ __forceinline__ short f2hs(float f) {
    __half h = __float2half(f);
    short s; __builtin_memcpy(&s, &h, 2); return s;
}
__device__ __forceinline__ __half2 h2shfl_xor(__half2 v, int off) {
    unsigned u; __builtin_memcpy(&u, &v, 4);
    u = __shfl_xor(u, off);
    __half2 r; __builtin_memcpy(&r, &u, 4);
    return r;
}

// A-frag from swizzled LDS tile hs[16][128] (bf16 shorts, col ^ ((row&7)<<3))
__device__ __forceinline__ bf16x8 lda(const short* hs, int lane, int ks) {
    int r = lane & 15, g = lane >> 4;
    int col = (ks * 32 + g * 8) ^ ((r & 7) << 3);
    return *(const bf16x8*)(hs + r * 128 + col);
}

__device__ __forceinline__ float wave_rsum(float s) {
    s += __shfl_xor(s, 32); s += __shfl_xor(s, 16); s += __shfl_xor(s, 8);
    s += __shfl_xor(s, 4);  s += __shfl_xor(s, 2);  s += __shfl_xor(s, 1);
    return s;
}

// ---------- weight prep: fp32 -> bf16 fragment-order, coalesced bf16x8 stores ----------
__global__ __launch_bounds__(512) void k_prep(
    const float* __restrict__ wq, const float* __restrict__ wk,
    const float* __restrict__ wv, const float* __restrict__ wo,
    const float* __restrict__ gw, const float* __restrict__ uw,
    const float* __restrict__ dw, short* __restrict__ wsw)
{
    int id = blockIdx.x * 512 + threadIdx.x;   // [0, 32768)
    const float* src; int base, ct, ks, lane, N, KS;
    if (id < 8192) {
        int m = id >> 11, loc = id & 2047;
        src = (m == 0) ? wq : (m == 1) ? wk : (m == 2) ? wv : wo;
        base = m << 14; N = 128; KS = 4;
        ct = loc >> 8; ks = (loc >> 6) & 3; lane = loc & 63;
    } else if (id < 16384) {
        int loc = id - 8192;
        src = gw; base = 65536; N = 512; KS = 4;
        ct = loc >> 8; ks = (loc >> 6) & 3; lane = loc & 63;
    } else if (id < 24576) {
        int loc = id - 16384;
        src = uw; base = 131072; N = 512; KS = 4;
        ct = loc >> 8; ks = (loc >> 6) & 3; lane = loc & 63;
    } else {
        int loc = id - 24576;
        src = dw; base = 196608; N = 128; KS = 16;
        ct = loc >> 10; ks = (loc >> 6) & 15; lane = loc & 63;
    }
    int k0 = ks * 32 + (lane >> 4) * 8;
    int c  = ct * 16 + (lane & 15);
    bf16x8 v;
    #pragma unroll
    for (int j = 0; j < 8; j++) v[j] = f2bs(src[(size_t)(k0 + j) * N + c]);
    *(bf16x8*)(wsw + base + (((ct * KS + ks) * 64 + lane) << 3)) = v;
}

// ---------- K1: rmsnorm(x)*n1 -> q,k,v (fp16); grid (256 rowtiles, 3 mats) ----------
__global__ __launch_bounds__(256) void k_qkv(
    const float* __restrict__ x, const float* __restrict__ n1,
    const short* __restrict__ wsw,
    short* __restrict__ qh, short* __restrict__ kh, short* __restrict__ vh)
{
    __shared__ short hs[2048];
    const int r0 = blockIdx.x * 16, m = blockIdx.y, t = threadIdx.x;
    const int w = t >> 6, lane = t & 63;

    // per-wave rmsnorm: wave w owns rows 4w..4w+3
    #pragma unroll
    for (int i = 0; i < 4; i++) {
        int r = w * 4 + i;
        const float* xp = x + (size_t)(r0 + r) * 128;
        float v0 = xp[lane], v1 = xp[lane + 64];
        float s = wave_rsum(fmaf(v0, v0, v1 * v1));
        float sc = rsqrtf(s * (1.0f / 128.0f) + EPSF);
        int p3 = (r & 7) << 3;
        hs[r * 128 + (lane ^ p3)]        = f2bs(v0 * sc * n1[lane]);
        hs[r * 128 + ((lane + 64) ^ p3)] = f2bs(v1 * sc * n1[lane + 64]);
    }
    __syncthreads();

    bf16x8 af[4];
    #pragma unroll
    for (int ks = 0; ks < 4; ks++) af[ks] = lda(hs, lane, ks);

    const int rb = (lane >> 4) * 4, cl = lane & 15, cb = w * 32;
    const short* wb = wsw + (m << 14);
    f32x4 a0 = {0.f,0.f,0.f,0.f}, a1 = {0.f,0.f,0.f,0.f};
    #pragma unroll
    for (int ks = 0; ks < 4; ks++) {
        bf16x8 b0 = *(const bf16x8*)(wb + ((((w * 2) * 4 + ks) * 64 + lane) << 3));
        bf16x8 b1 = *(const bf16x8*)(wb + ((((w * 2 + 1) * 4 + ks) * 64 + lane) << 3));
        a0 = __builtin_amdgcn_mfma_f32_16x16x32_bf16(af[ks], b0, a0, 0, 0, 0);
        a1 = __builtin_amdgcn_mfma_f32_16x16x32_bf16(af[ks], b1, a1, 0, 0, 0);
    }
    short* outp = (m == 0) ? qh : (m == 1) ? kh : vh;
    #pragma unroll
    for (int i = 0; i < 4; i++) {
        outp[(size_t)(r0 + rb + i) * 128 + cb + cl]      = f2hs(a0[i]);
        outp[(size_t)(r0 + rb + i) * 128 + cb + 16 + cl] = f2hs(a1[i]);
    }
}

// ---------- K2: brick-tiled local attention, fp16 packed math ----------
__global__ __launch_bounds__(256) void k_attn(
    const short* __restrict__ qh, const short* __restrict__ kh,
    const short* __restrict__ vh, short* __restrict__ obf)
{
    __shared__ short K_lds[384 * 40];
    __shared__ short V_lds[384 * 40];
    __shared__ int tab[125];

    const int b = blockIdx.x, head = blockIdx.y, t = threadIdx.x;
    const int ow = (b & 3) * 4, oh = ((b >> 2) & 3) * 4, od = (b >> 4) * 2;

    if (t < 125) {
        int dd = t / 25, rem = t % 25;
        tab[t] = dd | ((rem / 5) << 4) | ((rem % 5) << 8);
    }
    for (int row = t; row < 384; row += 256) {
        int lw = row & 7, lh = (row >> 3) & 7, ld = row >> 6;
        int gd = od - 2 + ld, gh = oh - 2 + lh, gw_ = ow - 2 + lw;
        uint4 kc[4], vc[4];
        if (((unsigned)gd < 16u) && ((unsigned)gh < 16u) && ((unsigned)gw_ < 16u)) {
            size_t off = ((size_t)(((gd << 4) | gh) << 4 | gw_)) * 128 + head * 32;
            #pragma unroll
            for (int c2 = 0; c2 < 4; c2++) {
                kc[c2] = *(const uint4*)(kh + off + c2 * 8);
                vc[c2] = *(const uint4*)(vh + off + c2 * 8);
            }
        } else {
            #pragma unroll
            for (int c2 = 0; c2 < 4; c2++) { kc[c2] = (uint4){0,0,0,0}; vc[c2] = (uint4){0,0,0,0}; }
        }
        #pragma unroll
        for (int c2 = 0; c2 < 4; c2++) {
            *(uint4*)&K_lds[row * 40 + c2 * 8] = kc[c2];
            *(uint4*)&V_lds[row * 40 + c2 * 8] = vc[c2];
        }
    }
    __syncthreads();

    const int qi = t >> 3, qt = t & 7;           // 32 queries x 8 lanes
    const int qw_ = qi & 3, qh_ = (qi >> 2) & 3, qd_ = qi >> 4;
    const int gqd = od + qd_, gqh = oh + qh_, gqw = ow + qw_;
    const int gvox = (((gqd << 4) | gqh) << 4) | gqw;
    const int base = (qd_ + 2) * 64 + (qh_ + 2) * 8 + (qw_ + 2);

    __half2 q2[16];
    {
        const __half2 isq2 = __float2half2_rn(0.17677669529663687f);  // 1/sqrt(32)
        const short* qp = qh + (size_t)gvox * 128 + head * 32;
        #pragma unroll
        for (int c2 = 0; c2 < 4; c2++) {
            uint4 raw = *(const uint4*)(qp + c2 * 8);
            __half2 h4[4]; __builtin_memcpy(h4, &raw, 16);
            #pragma unroll
            for (int j = 0; j < 4; j++) q2[c2 * 4 + j] = __hmul2(h4[j], isq2);
        }
    }

    float sc[16]; int hid[16];
    float m = -1e30f;
    const int kk0 = qt * 16;
    #pragma unroll
    for (int i = 0; i < 16; i++) {
        int kk = kk0 + i;
        float s = -1e30f; int h = 0;
        if (kk < 125) {
            int tt = tab[kk];
            int dd = (tt & 15) - 2, dh = ((tt >> 4) & 15) - 2, dw_ = (tt >> 8) - 2;
            if (((unsigned)(gqd + dd) < 16u) & ((unsigned)(gqh + dh) < 16u) & ((unsigned)(gqw + dw_) < 16u)) {
                h = base + dd * 64 + dh * 8 + dw_;
                __half2 a0 = __float2half2_rn(0.f), a1 = __float2half2_rn(0.f);
                __half2 a2 = __float2half2_rn(0.f), a3 = __float2half2_rn(0.f);
                #pragma unroll
                for (int c2 = 0; c2 < 4; c2++) {
                    uint4 raw = *(const uint4*)&K_lds[h * 40 + c2 * 8];
                    __half2 k4[4]; __builtin_memcpy(k4, &raw, 16);
                    a0 = __hfma2(q2[c2 * 4 + 0], k4[0], a0);
                    a1 = __hfma2(q2[c2 * 4 + 1], k4[1], a1);
                    a2 = __hfma2(q2[c2 * 4 + 2], k4[2], a2);
                    a3 = __hfma2(q2[c2 * 4 + 3], k4[3], a3);
                }
                __half2 at = __hadd2(__hadd2(a0, a1), __hadd2(a2, a3));
                s = __low2float(at) + __high2float(at);
            }
        }
        sc[i] = s; hid[i] = h;
        m = fmaxf(m, s);
    }
    m = fmaxf(m, __shfl_xor(m, 1));
    m = fmaxf(m, __shfl_xor(m, 2));
    m = fmaxf(m, __shfl_xor(m, 4));
    float ssum = 0.f;
    #pragma unroll
    for (int i = 0; i < 16; i++) {
        float p = (sc[i] > -1e29f) ? __expf(sc[i] - m) : 0.f;
        sc[i] = p; ssum += p;
    }
    ssum += __shfl_xor(ssum, 1);
    ssum += __shfl_xor(ssum, 2);
    ssum += __shfl_xor(ssum, 4);
    const float inv = 1.0f / ssum;

    __half2 acc2[16];
    #pragma unroll
    for (int c2 = 0; c2 < 16; c2++) acc2[c2] = __float2half2_rn(0.f);
    #pragma unroll
    for (int i = 0; i < 16; i++) {
        __half2 pp = __float2half2_rn(sc[i]);
        int h = hid[i];
        #pragma unroll
        for (int c2 = 0; c2 < 4; c2++) {
            uint4 raw = *(const uint4*)&V_lds[h * 40 + c2 * 8];
            __half2 v4[4]; __builtin_memcpy(v4, &raw, 16);
            acc2[c2 * 4 + 0] = __hfma2(pp, v4[0], acc2[c2 * 4 + 0]);
            acc2[c2 * 4 + 1] = __hfma2(pp, v4[1], acc2[c2 * 4 + 1]);
            acc2[c2 * 4 + 2] = __hfma2(pp, v4[2], acc2[c2 * 4 + 2]);
            acc2[c2 * 4 + 3] = __hfma2(pp, v4[3], acc2[c2 * 4 + 3]);
        }
    }
    #pragma unroll
    for (int c2 = 0; c2 < 16; c2++) {
        acc2[c2] = __hadd2(acc2[c2], h2shfl_xor(acc2[c2], 1));
        acc2[c2] = __hadd2(acc2[c2], h2shfl_xor(acc2[c2], 2));
        acc2[c2] = __hadd2(acc2[c2], h2shfl_xor(acc2[c2], 4));
    }
    // lane qt owns channels 4qt..4qt+3 = acc2[2qt], acc2[2qt+1]
    short o4[4];
    o4[0] = f2bs(__low2float(acc2[qt * 2])      * inv);
    o4[1] = f2bs(__high2float(acc2[qt * 2])     * inv);
    o4[2] = f2bs(__low2float(acc2[qt * 2 + 1])  * inv);
    o4[3] = f2bs(__high2float(acc2[qt * 2 + 1]) * inv);
    unsigned long long pk; __builtin_memcpy(&pk, o4, 8);
    *(unsigned long long*)&obf[(size_t)gvox * 128 + head * 32 + qt * 4] = pk;
}

// ---------- K3: fused post-chain (round-9 proven) ----------
__global__ __launch_bounds__(256) void k_post(
    const short* __restrict__ obf, const short* __restrict__ wsw,
    const float* __restrict__ anw, const float* __restrict__ x,
    const float* __restrict__ n2w, float* __restrict__ out)
{
    __shared__ float ybuf[16][132];
    __shared__ float xres[16][128];
    __shared__ short hs[2048];
    __shared__ short gu[16 * 512];

    const int r0 = blockIdx.x * 16, t = threadIdx.x;
    const int w = t >> 6, lane = t & 63;
    const int ar = lane & 15, ag_ = lane >> 4;

    // phase 1: y = o @ wo
    {
        const short* wb = wsw + (3 << 14);
        f32x4 a0 = {0.f,0.f,0.f,0.f}, a1 = {0.f,0.f,0.f,0.f};
        #pragma unroll
        for (int ks = 0; ks < 4; ks++) {
            bf16x8 a = *(const bf16x8*)(obf + (size_t)(r0 + ar) * 128 + ks * 32 + ag_ * 8);
            bf16x8 b0 = *(const bf16x8*)(wb + ((((w * 2) * 4 + ks) * 64 + lane) << 3));
            bf16x8 b1 = *(const bf16x8*)(wb + ((((w * 2 + 1) * 4 + ks) * 64 + lane) << 3));
            a0 = __builtin_amdgcn_mfma_f32_16x16x32_bf16(a, b0, a0, 0, 0, 0);
            a1 = __builtin_amdgcn_mfma_f32_16x16x32_bf16(a, b1, a1, 0, 0, 0);
        }
        #pragma unroll
        for (int i = 0; i < 4; i++) {
            ybuf[ag_ * 4 + i][w * 32 + ar]      = a0[i];
            ybuf[ag_ * 4 + i][w * 32 + 16 + ar] = a1[i];
        }
    }
    __syncthreads();

    // phase 2+3 fused, per-wave: xres = x + rmsnorm(y)*anw; hs = rmsnorm(xres)*n2w
    #pragma unroll
    for (int i = 0; i < 4; i++) {
        int r = w * 4 + i;
        float y0 = ybuf[r][lane], y1 = ybuf[r][lane + 64];
        float s = wave_rsum(fmaf(y0, y0, y1 * y1));
        float sc = rsqrtf(s * (1.0f / 128.0f) + EPSF);
        const float* xp = x + (size_t)(r0 + r) * 128;
        float xr0 = xp[lane]      + y0 * sc * anw[lane];
        float xr1 = xp[lane + 64] + y1 * sc * anw[lane + 64];
        xres[r][lane] = xr0; xres[r][lane + 64] = xr1;
        float s2 = wave_rsum(fmaf(xr0, xr0, xr1 * xr1));
        float sc2 = rsqrtf(s2 * (1.0f / 128.0f) + EPSF);
        int p3 = (r & 7) << 3;
        hs[r * 128 + (lane ^ p3)]        = f2bs(xr0 * sc2 * n2w[lane]);
        hs[r * 128 + ((lane + 64) ^ p3)] = f2bs(xr1 * sc2 * n2w[lane + 64]);
    }
    __syncthreads();

    // phase 4: gu = silu(h2@gw)*(h2@uw)
    {
        const short* gwb = wsw + 65536;
        const short* uwb = wsw + 131072;
        bf16x8 af[4];
        #pragma unroll
        for (int ks = 0; ks < 4; ks++) af[ks] = lda(hs, lane, ks);
        f32x4 ag[8], au[8];
        #pragma unroll
        for (int i = 0; i < 8; i++) { ag[i] = (f32x4){0.f,0.f,0.f,0.f}; au[i] = (f32x4){0.f,0.f,0.f,0.f}; }
        #pragma unroll
        for (int ks = 0; ks < 4; ks++) {
            #pragma unroll
            for (int i = 0; i < 8; i++) {
                int ct = w * 8 + i;
                bf16x8 bg = *(const bf16x8*)(gwb + (((ct * 4 + ks) * 64 + lane) << 3));
                bf16x8 bu = *(const bf16x8*)(uwb + (((ct * 4 + ks) * 64 + lane) << 3));
                ag[i] = __builtin_amdgcn_mfma_f32_16x16x32_bf16(af[ks], bg, ag[i], 0, 0, 0);
                au[i] = __builtin_amdgcn_mfma_f32_16x16x32_bf16(af[ks], bu, au[i], 0, 0, 0);
            }
        }
        #pragma unroll
        for (int i = 0; i < 8; i++) {
            int col = (w * 8 + i) * 16 + ar;
            #pragma unroll
            for (int j = 0; j < 4; j++) {
                int row = ag_ * 4 + j;
                float g = ag[i][j], uu = au[i][j];
                float sg = g / (1.0f + __expf(-g));
                gu[row * 512 + (col ^ ((row & 7) << 3))] = f2bs(sg * uu);
            }
        }
    }
    __syncthreads();

    // phase 5: out = xres + gu @ dw (K=512)
    {
        const short* db = wsw + 196608;
        f32x4 a0 = {0.f,0.f,0.f,0.f}, a1 = {0.f,0.f,0.f,0.f};
        #pragma unroll
        for (int ks = 0; ks < 16; ks++) {
            int col = (ks * 32 + ag_ * 8) ^ ((ar & 7) << 3);
            bf16x8 a = *(const bf16x8*)(gu + ar * 512 + col);
            bf16x8 b0 = *(const bf16x8*)(db + ((((w * 2) * 16 + ks) * 64 + lane) << 3));
            bf16x8 b1 = *(const bf16x8*)(db + ((((w * 2 + 1) * 16 + ks) * 64 + lane) << 3));
            a0 = __builtin_amdgcn_mfma_f32_16x16x32_bf16(a, b0, a0, 0, 0, 0);
            a1 = __builtin_amdgcn_mfma_f32_16x16x32_bf16(a, b1, a1, 0, 0, 0);
        }
        #pragma unroll
        for (int i = 0; i < 4; i++) {
            int row = ag_ * 4 + i;
            size_t i0 = (size_t)(r0 + row) * 128 + w * 32 + ar;
            out[i0]      = xres[row][w * 32 + ar]      + a0[i];
            out[i0 + 16] = xres[row][w * 32 + 16 + ar] + a1[i];
        }
    }
}

extern "C" void kernel_launch(void* const* d_in, const int* in_sizes, int n_in,
                              void* d_out, int out_size, void* d_ws, size_t ws_size,
                              hipStream_t stream)
{
    const float* x   = (const float*)d_in[0];
    const float* n1  = (const float*)d_in[1];
    const float* anw = (const float*)d_in[2];
    const float* n2  = (const float*)d_in[3];
    const float* wq  = (const float*)d_in[4];
    const float* wk  = (const float*)d_in[5];
    const float* wv  = (const float*)d_in[6];
    const float* wo  = (const float*)d_in[7];
    const float* gw  = (const float*)d_in[8];
    const float* uw  = (const float*)d_in[9];
    const float* dw  = (const float*)d_in[10];
    float* out = (float*)d_out;

    float* ws = (float*)d_ws;
    short* qh  = (short*)ws;                   // fp16 bits
    short* kh  = (short*)(ws + 262144);        // fp16 bits
    short* vh  = (short*)(ws + 524288);        // fp16 bits
    short* obf = (short*)(ws + 786432);        // bf16 bits
    short* wsw = (short*)(ws + 1048576);       // bf16 fragment-order weights

    k_prep<<<64, 512, 0, stream>>>(wq, wk, wv, wo, gw, uw, dw, wsw);
    dim3 gq(256, 3);
    k_qkv <<<gq,  256, 0, stream>>>(x, n1, wsw, qh, kh, vh);
    dim3 ga(128, 4);
    k_attn<<<ga,  256, 0, stream>>>(qh, kh, vh, obf);
    k_post<<<256, 256, 0, stream>>>(obf, wsw, anw, x, n2, out);
}

// Round 13
// 42.365 us; speedup vs baseline: 4.4359x; 1.2091x over previous
//
#include <hip/hip_runtime.h>
#include <hip/hip_bf16.h>

#define NVOX 4096
#define C    128
#define HID  512
#define EPSF 1e-6f

typedef __attribute__((ext_vector_type(8))) short bf16x8;
typedef __attribute__((ext_vector_type(4))) float f32x4;

__device__ __forceinline__ short f2bs(float f) {
    __hip_bfloat16 h = __float2bfloat16(f);
    short s; __builtin_memcpy(&s, &h, 2); return s;
}
__device__ __forceinline__ float bs2f(unsigned short u) {
    return __uint_as_float(((unsigned)u) << 16);
}

// A-frag from swizzled LDS tile hs[16][128] (bf16 shorts, col ^ ((row&7)<<3))
__device__ __forceinline__ bf16x8 lda(const short* hs, int lane, int ks) {
    int r = lane & 15, g = lane >> 4;
    int col = (ks * 32 + g * 8) ^ ((r & 7) << 3);
    return *(const bf16x8*)(hs + r * 128 + col);
}

__device__ __forceinline__ float wave_rsum(float s) {
    s += __shfl_xor(s, 32); s += __shfl_xor(s, 16); s += __shfl_xor(s, 8);
    s += __shfl_xor(s, 4);  s += __shfl_xor(s, 2);  s += __shfl_xor(s, 1);
    return s;
}

// K/V halo row: stride 40 shorts (start bank 20h mod 32, 8 classes by h mod 8).
// Within-row chunk ROTATION (bijective, row-contained): logical chunk c2 lives at
// ((c2 + rot(h)) & 3) * 8, rot = (lh + ld) & 3 -> same-class lanes (same h mod 8,
// differing lh/ld) spread across 4 bank groups: ~8-way -> ~2-way (free).
__device__ __forceinline__ int kv_rot(int h) {
    return ((h >> 3) + (h >> 6)) & 3;
}

// ---------- weight prep: fp32 -> bf16 fragment-order, coalesced bf16x8 stores ----------
__global__ __launch_bounds__(512) void k_prep(
    const float* __restrict__ wq, const float* __restrict__ wk,
    const float* __restrict__ wv, const float* __restrict__ wo,
    const float* __restrict__ gw, const float* __restrict__ uw,
    const float* __restrict__ dw, short* __restrict__ wsw)
{
    int id = blockIdx.x * 512 + threadIdx.x;   // [0, 32768)
    const float* src; int base, ct, ks, lane, N, KS;
    if (id < 8192) {
        int m = id >> 11, loc = id & 2047;
        src = (m == 0) ? wq : (m == 1) ? wk : (m == 2) ? wv : wo;
        base = m << 14; N = 128; KS = 4;
        ct = loc >> 8; ks = (loc >> 6) & 3; lane = loc & 63;
    } else if (id < 16384) {
        int loc = id - 8192;
        src = gw; base = 65536; N = 512; KS = 4;
        ct = loc >> 8; ks = (loc >> 6) & 3; lane = loc & 63;
    } else if (id < 24576) {
        int loc = id - 16384;
        src = uw; base = 131072; N = 512; KS = 4;
        ct = loc >> 8; ks = (loc >> 6) & 3; lane = loc & 63;
    } else {
        int loc = id - 24576;
        src = dw; base = 196608; N = 128; KS = 16;
        ct = loc >> 10; ks = (loc >> 6) & 15; lane = loc & 63;
    }
    int k0 = ks * 32 + (lane >> 4) * 8;
    int c  = ct * 16 + (lane & 15);
    bf16x8 v;
    #pragma unroll
    for (int j = 0; j < 8; j++) v[j] = f2bs(src[(size_t)(k0 + j) * N + c]);
    *(bf16x8*)(wsw + base + (((ct * KS + ks) * 64 + lane) << 3)) = v;
}

// ---------- K1: rmsnorm(x)*n1 -> q(bf16), k(bf16), v(bf16); 256 thr ----------
__global__ __launch_bounds__(256) void k_qkv(
    const float* __restrict__ x, const float* __restrict__ n1,
    const short* __restrict__ wsw,
    short* __restrict__ qbf, short* __restrict__ kbf, short* __restrict__ vbf)
{
    __shared__ short hs[2048];
    const int r0 = blockIdx.x * 16, t = threadIdx.x;
    const int w = t >> 6, lane = t & 63;

    // per-wave rmsnorm: wave w owns rows 4w..4w+3 (no block barriers)
    #pragma unroll
    for (int i = 0; i < 4; i++) {
        int r = w * 4 + i;
        const float* xp = x + (size_t)(r0 + r) * 128;
        float v0 = xp[lane], v1 = xp[lane + 64];
        float s = wave_rsum(fmaf(v0, v0, v1 * v1));
        float sc = rsqrtf(s * (1.0f / 128.0f) + EPSF);
        int p3 = (r & 7) << 3;
        hs[r * 128 + (lane ^ p3)]        = f2bs(v0 * sc * n1[lane]);
        hs[r * 128 + ((lane + 64) ^ p3)] = f2bs(v1 * sc * n1[lane + 64]);
    }
    __syncthreads();

    bf16x8 af[4];
    #pragma unroll
    for (int ks = 0; ks < 4; ks++) af[ks] = lda(hs, lane, ks);

    const int rb = (lane >> 4) * 4, cl = lane & 15, cb = w * 32;
    #pragma unroll
    for (int m = 0; m < 3; m++) {
        const short* wb = wsw + (m << 14);
        f32x4 a0 = {0.f,0.f,0.f,0.f}, a1 = {0.f,0.f,0.f,0.f};
        #pragma unroll
        for (int ks = 0; ks < 4; ks++) {
            bf16x8 b0 = *(const bf16x8*)(wb + ((((w * 2) * 4 + ks) * 64 + lane) << 3));
            bf16x8 b1 = *(const bf16x8*)(wb + ((((w * 2 + 1) * 4 + ks) * 64 + lane) << 3));
            a0 = __builtin_amdgcn_mfma_f32_16x16x32_bf16(af[ks], b0, a0, 0, 0, 0);
            a1 = __builtin_amdgcn_mfma_f32_16x16x32_bf16(af[ks], b1, a1, 0, 0, 0);
        }
        short* outp = (m == 0) ? qbf : (m == 1) ? kbf : vbf;
        #pragma unroll
        for (int i = 0; i < 4; i++) {
            outp[(size_t)(r0 + rb + i) * 128 + cb + cl]      = f2bs(a0[i]);
            outp[(size_t)(r0 + rb + i) * 128 + cb + 16 + cl] = f2bs(a1[i]);
        }
    }
}

// ---------- K2: brick-tiled local attention (rotated K/V chunk layout) ----------
__global__ __launch_bounds__(256) void k_attn(
    const short* __restrict__ qbf, const short* __restrict__ kbf,
    const short* __restrict__ vbf, short* __restrict__ obf)
{
    __shared__ short K_lds[384 * 40];
    __shared__ short V_lds[384 * 40];
    __shared__ int tab[125];

    const int b = blockIdx.x, head = blockIdx.y, t = threadIdx.x;
    const int ow = (b & 3) * 4, oh = ((b >> 2) & 3) * 4, od = (b >> 4) * 2;

    if (t < 125) {
        int dd = t / 25, rem = t % 25;
        tab[t] = dd | ((rem / 5) << 4) | ((rem % 5) << 8);
    }
    for (int row = t; row < 384; row += 256) {
        int lw = row & 7, lh = (row >> 3) & 7, ld = row >> 6;
        int gd = od - 2 + ld, gh = oh - 2 + lh, gw_ = ow - 2 + lw;
        uint4 kc[4], vc[4];
        if (((unsigned)gd < 16u) && ((unsigned)gh < 16u) && ((unsigned)gw_ < 16u)) {
            size_t off = ((size_t)(((gd << 4) | gh) << 4 | gw_)) * 128 + head * 32;
            #pragma unroll
            for (int c2 = 0; c2 < 4; c2++) {
                kc[c2] = *(const uint4*)(kbf + off + c2 * 8);
                vc[c2] = *(const uint4*)(vbf + off + c2 * 8);
            }
        } else {
            #pragma unroll
            for (int c2 = 0; c2 < 4; c2++) { kc[c2] = (uint4){0,0,0,0}; vc[c2] = (uint4){0,0,0,0}; }
        }
        int ro = row * 40, rot = kv_rot(row);
        #pragma unroll
        for (int c2 = 0; c2 < 4; c2++) {
            int p = ((c2 + rot) & 3) << 3;
            *(uint4*)&K_lds[ro + p] = kc[c2];
            *(uint4*)&V_lds[ro + p] = vc[c2];
        }
    }
    __syncthreads();

    const int qi = t >> 3, qt = t & 7;           // 32 queries x 8 lanes
    const int qw_ = qi & 3, qh_ = (qi >> 2) & 3, qd_ = qi >> 4;
    const int gqd = od + qd_, gqh = oh + qh_, gqw = ow + qw_;
    const int gvox = (((gqd << 4) | gqh) << 4) | gqw;
    const int base = (qd_ + 2) * 64 + (qh_ + 2) * 8 + (qw_ + 2);

    float qreg[32];
    {
        const float isq = 0.17677669529663687f;  // 1/sqrt(32)
        const short* qp = qbf + (size_t)gvox * 128 + head * 32;
        #pragma unroll
        for (int c2 = 0; c2 < 4; c2++) {
            uint4 raw = *(const uint4*)(qp + c2 * 8);
            const unsigned short* u = (const unsigned short*)&raw;
            #pragma unroll
            for (int j = 0; j < 8; j++) qreg[c2 * 8 + j] = bs2f(u[j]) * isq;
        }
    }

    float sc[16]; int hid[16];
    float m = -1e30f;
    const int kk0 = qt * 16;
    #pragma unroll
    for (int i = 0; i < 16; i++) {
        int kk = kk0 + i;
        float s = -1e30f; int h = 0;
        if (kk < 125) {
            int tt = tab[kk];
            int dd = (tt & 15) - 2, dh = ((tt >> 4) & 15) - 2, dw_ = (tt >> 8) - 2;
            if (((unsigned)(gqd + dd) < 16u) & ((unsigned)(gqh + dh) < 16u) & ((unsigned)(gqw + dw_) < 16u)) {
                h = base + dd * 64 + dh * 8 + dw_;
                int ro = h * 40, rot = kv_rot(h);
                float acc = 0.f;
                #pragma unroll
                for (int c2 = 0; c2 < 4; c2++) {
                    uint4 raw = *(const uint4*)&K_lds[ro + ((((c2 + rot) & 3)) << 3)];
                    const unsigned short* u = (const unsigned short*)&raw;
                    #pragma unroll
                    for (int j = 0; j < 8; j++) acc = fmaf(qreg[c2 * 8 + j], bs2f(u[j]), acc);
                }
                s = acc;
            }
        }
        sc[i] = s; hid[i] = h;
        m = fmaxf(m, s);
    }
    m = fmaxf(m, __shfl_xor(m, 1));
    m = fmaxf(m, __shfl_xor(m, 2));
    m = fmaxf(m, __shfl_xor(m, 4));
    float ssum = 0.f;
    #pragma unroll
    for (int i = 0; i < 16; i++) {
        float p = (sc[i] > -1e29f) ? __expf(sc[i] - m) : 0.f;
        sc[i] = p; ssum += p;
    }
    ssum += __shfl_xor(ssum, 1);
    ssum += __shfl_xor(ssum, 2);
    ssum += __shfl_xor(ssum, 4);
    const float inv = 1.0f / ssum;

    float acc[32];
    #pragma unroll
    for (int c2 = 0; c2 < 32; c2++) acc[c2] = 0.f;
    #pragma unroll
    for (int i = 0; i < 16; i++) {
        float p = sc[i];
        int h = hid[i];
        int ro = h * 40, rot = kv_rot(h);
        #pragma unroll
        for (int c2 = 0; c2 < 4; c2++) {
            uint4 raw = *(const uint4*)&V_lds[ro + ((((c2 + rot) & 3)) << 3)];
            const unsigned short* u = (const unsigned short*)&raw;
            #pragma unroll
            for (int j = 0; j < 8; j++) acc[c2 * 8 + j] = fmaf(p, bs2f(u[j]), acc[c2 * 8 + j]);
        }
    }
    #pragma unroll
    for (int c2 = 0; c2 < 32; c2++) {
        acc[c2] += __shfl_xor(acc[c2], 1);
        acc[c2] += __shfl_xor(acc[c2], 2);
        acc[c2] += __shfl_xor(acc[c2], 4);
    }
    short o4[4];
    #pragma unroll
    for (int j = 0; j < 4; j++) o4[j] = f2bs(acc[qt * 4 + j] * inv);
    unsigned long long pk; __builtin_memcpy(&pk, o4, 8);
    *(unsigned long long*)&obf[(size_t)gvox * 128 + head * 32 + qt * 4] = pk;
}

// ---------- K3: fused post-chain, 3 barriers (per-wave rmsnorms) ----------
__global__ __launch_bounds__(256) void k_post(
    const short* __restrict__ obf, const short* __restrict__ wsw,
    const float* __restrict__ anw, const float* __restrict__ x,
    const float* __restrict__ n2w, float* __restrict__ out)
{
    __shared__ float ybuf[16][132];
    __shared__ float xres[16][128];
    __shared__ short hs[2048];
    __shared__ short gu[16 * 512];

    const int r0 = blockIdx.x * 16, t = threadIdx.x;
    const int w = t >> 6, lane = t & 63;
    const int ar = lane & 15, ag_ = lane >> 4;

    // phase 1: y = o @ wo
    {
        const short* wb = wsw + (3 << 14);
        f32x4 a0 = {0.f,0.f,0.f,0.f}, a1 = {0.f,0.f,0.f,0.f};
        #pragma unroll
        for (int ks = 0; ks < 4; ks++) {
            bf16x8 a = *(const bf16x8*)(obf + (size_t)(r0 + ar) * 128 + ks * 32 + ag_ * 8);
            bf16x8 b0 = *(const bf16x8*)(wb + ((((w * 2) * 4 + ks) * 64 + lane) << 3));
            bf16x8 b1 = *(const bf16x8*)(wb + ((((w * 2 + 1) * 4 + ks) * 64 + lane) << 3));
            a0 = __builtin_amdgcn_mfma_f32_16x16x32_bf16(a, b0, a0, 0, 0, 0);
            a1 = __builtin_amdgcn_mfma_f32_16x16x32_bf16(a, b1, a1, 0, 0, 0);
        }
        #pragma unroll
        for (int i = 0; i < 4; i++) {
            ybuf[ag_ * 4 + i][w * 32 + ar]      = a0[i];
            ybuf[ag_ * 4 + i][w * 32 + 16 + ar] = a1[i];
        }
    }
    __syncthreads();

    // phase 2+3 fused, per-wave: xres = x + rmsnorm(y)*anw; hs = rmsnorm(xres)*n2w
    #pragma unroll
    for (int i = 0; i < 4; i++) {
        int r = w * 4 + i;
        float y0 = ybuf[r][lane], y1 = ybuf[r][lane + 64];
        float s = wave_rsum(fmaf(y0, y0, y1 * y1));
        float sc = rsqrtf(s * (1.0f / 128.0f) + EPSF);
        const float* xp = x + (size_t)(r0 + r) * 128;
        float xr0 = xp[lane]      + y0 * sc * anw[lane];
        float xr1 = xp[lane + 64] + y1 * sc * anw[lane + 64];
        xres[r][lane] = xr0; xres[r][lane + 64] = xr1;
        float s2 = wave_rsum(fmaf(xr0, xr0, xr1 * xr1));
        float sc2 = rsqrtf(s2 * (1.0f / 128.0f) + EPSF);
        int p3 = (r & 7) << 3;
        hs[r * 128 + (lane ^ p3)]        = f2bs(xr0 * sc2 * n2w[lane]);
        hs[r * 128 + ((lane + 64) ^ p3)] = f2bs(xr1 * sc2 * n2w[lane + 64]);
    }
    __syncthreads();

    // phase 4: gu = silu(h2@gw)*(h2@uw)  (4 waves x 8 col-tiles)
    {
        const short* gwb = wsw + 65536;
        const short* uwb = wsw + 131072;
        bf16x8 af[4];
        #pragma unroll
        for (int ks = 0; ks < 4; ks++) af[ks] = lda(hs, lane, ks);
        f32x4 ag[8], au[8];
        #pragma unroll
        for (int i = 0; i < 8; i++) { ag[i] = (f32x4){0.f,0.f,0.f,0.f}; au[i] = (f32x4){0.f,0.f,0.f,0.f}; }
        #pragma unroll
        for (int ks = 0; ks < 4; ks++) {
            #pragma unroll
            for (int i = 0; i < 8; i++) {
                int ct = w * 8 + i;
                bf16x8 bg = *(const bf16x8*)(gwb + (((ct * 4 + ks) * 64 + lane) << 3));
                bf16x8 bu = *(const bf16x8*)(uwb + (((ct * 4 + ks) * 64 + lane) << 3));
                ag[i] = __builtin_amdgcn_mfma_f32_16x16x32_bf16(af[ks], bg, ag[i], 0, 0, 0);
                au[i] = __builtin_amdgcn_mfma_f32_16x16x32_bf16(af[ks], bu, au[i], 0, 0, 0);
            }
        }
        #pragma unroll
        for (int i = 0; i < 8; i++) {
            int col = (w * 8 + i) * 16 + ar;
            #pragma unroll
            for (int j = 0; j < 4; j++) {
                int row = ag_ * 4 + j;
                float g = ag[i][j], uu = au[i][j];
                float sg = g / (1.0f + __expf(-g));
                gu[row * 512 + (col ^ ((row & 7) << 3))] = f2bs(sg * uu);
            }
        }
    }
    __syncthreads();

    // phase 5: out = xres + gu @ dw (K=512)
    {
        const short* db = wsw + 196608;
        f32x4 a0 = {0.f,0.f,0.f,0.f}, a1 = {0.f,0.f,0.f,0.f};
        #pragma unroll
        for (int ks = 0; ks < 16; ks++) {
            int col = (ks * 32 + ag_ * 8) ^ ((ar & 7) << 3);
            bf16x8 a = *(const bf16x8*)(gu + ar * 512 + col);
            bf16x8 b0 = *(const bf16x8*)(db + ((((w * 2) * 16 + ks) * 64 + lane) << 3));
            bf16x8 b1 = *(const bf16x8*)(db + ((((w * 2 + 1) * 16 + ks) * 64 + lane) << 3));
            a0 = __builtin_amdgcn_mfma_f32_16x16x32_bf16(a, b0, a0, 0, 0, 0);
            a1 = __builtin_amdgcn_mfma_f32_16x16x32_bf16(a, b1, a1, 0, 0, 0);
        }
        #pragma unroll
        for (int i = 0; i < 4; i++) {
            int row = ag_ * 4 + i;
            size_t i0 = (size_t)(r0 + row) * 128 + w * 32 + ar;
            out[i0]      = xres[row][w * 32 + ar]      + a0[i];
            out[i0 + 16] = xres[row][w * 32 + 16 + ar] + a1[i];
        }
    }
}

extern "C" void kernel_launch(void* const* d_in, const int* in_sizes, int n_in,
                              void* d_out, int out_size, void* d_ws, size_t ws_size,
                              hipStream_t stream)
{
    const float* x   = (const float*)d_in[0];
    const float* n1  = (const float*)d_in[1];
    const float* anw = (const float*)d_in[2];
    const float* n2  = (const float*)d_in[3];
    const float* wq  = (const float*)d_in[4];
    const float* wk  = (const float*)d_in[5];
    const float* wv  = (const float*)d_in[6];
    const float* wo  = (const float*)d_in[7];
    const float* gw  = (const float*)d_in[8];
    const float* uw  = (const float*)d_in[9];
    const float* dw  = (const float*)d_in[10];
    float* out = (float*)d_out;

    float* ws = (float*)d_ws;
    short* qbf = (short*)ws;                   // 524288 shorts
    short* kbf = (short*)(ws + 262144);
    short* vbf = (short*)(ws + 524288);
    short* obf = (short*)(ws + 786432);
    short* wsw = (short*)(ws + 1048576);       // 262144 shorts

    k_prep<<<64,  512, 0, stream>>>(wq, wk, wv, wo, gw, uw, dw, wsw);
    k_qkv <<<256, 256, 0, stream>>>(x, n1, wsw, qbf, kbf, vbf);
    dim3 ga(128, 4);
    k_attn<<<ga,  256, 0, stream>>>(qbf, kbf, vbf, obf);
    k_post<<<256, 256, 0, stream>>>(obf, wsw, anw, x, n2, out);
}

// Round 14
// 41.315 us; speedup vs baseline: 4.5486x; 1.0254x over previous
//
#include <hip/hip_runtime.h>
#include <hip/hip_bf16.h>

#define NVOX 4096
#define C    128
#define HID  512
#define EPSF 1e-6f

typedef __attribute__((ext_vector_type(8))) short bf16x8;
typedef __attribute__((ext_vector_type(4))) float f32x4;

__device__ __forceinline__ short f2bs(float f) {
    __hip_bfloat16 h = __float2bfloat16(f);
    short s; __builtin_memcpy(&s, &h, 2); return s;
}
__device__ __forceinline__ float bs2f(unsigned short u) {
    return __uint_as_float(((unsigned)u) << 16);
}

// A-frag from swizzled LDS tile hs[16][128] (bf16 shorts, col ^ ((row&7)<<3))
__device__ __forceinline__ bf16x8 lda(const short* hs, int lane, int ks) {
    int r = lane & 15, g = lane >> 4;
    int col = (ks * 32 + g * 8) ^ ((r & 7) << 3);
    return *(const bf16x8*)(hs + r * 128 + col);
}

__device__ __forceinline__ float wave_rsum(float s) {
    s += __shfl_xor(s, 32); s += __shfl_xor(s, 16); s += __shfl_xor(s, 8);
    s += __shfl_xor(s, 4);  s += __shfl_xor(s, 2);  s += __shfl_xor(s, 1);
    return s;
}

// K/V halo row: stride 40 shorts; within-row chunk rotation (bijective):
// logical chunk c2 at ((c2 + rot(h)) & 3)*8, rot = (lh + ld) & 3.
__device__ __forceinline__ int kv_rot(int h) {
    return ((h >> 3) + (h >> 6)) & 3;
}

// ---------- weight prep: fp32 -> bf16 fragment-order, coalesced bf16x8 stores ----------
__global__ __launch_bounds__(512) void k_prep(
    const float* __restrict__ wq, const float* __restrict__ wk,
    const float* __restrict__ wv, const float* __restrict__ wo,
    const float* __restrict__ gw, const float* __restrict__ uw,
    const float* __restrict__ dw, short* __restrict__ wsw)
{
    int id = blockIdx.x * 512 + threadIdx.x;   // [0, 32768)
    const float* src; int base, ct, ks, lane, N, KS;
    if (id < 8192) {
        int m = id >> 11, loc = id & 2047;
        src = (m == 0) ? wq : (m == 1) ? wk : (m == 2) ? wv : wo;
        base = m << 14; N = 128; KS = 4;
        ct = loc >> 8; ks = (loc >> 6) & 3; lane = loc & 63;
    } else if (id < 16384) {
        int loc = id - 8192;
        src = gw; base = 65536; N = 512; KS = 4;
        ct = loc >> 8; ks = (loc >> 6) & 3; lane = loc & 63;
    } else if (id < 24576) {
        int loc = id - 16384;
        src = uw; base = 131072; N = 512; KS = 4;
        ct = loc >> 8; ks = (loc >> 6) & 3; lane = loc & 63;
    } else {
        int loc = id - 24576;
        src = dw; base = 196608; N = 128; KS = 16;
        ct = loc >> 10; ks = (loc >> 6) & 15; lane = loc & 63;
    }
    int k0 = ks * 32 + (lane >> 4) * 8;
    int c  = ct * 16 + (lane & 15);
    bf16x8 v;
    #pragma unroll
    for (int j = 0; j < 8; j++) v[j] = f2bs(src[(size_t)(k0 + j) * N + c]);
    *(bf16x8*)(wsw + base + (((ct * KS + ks) * 64 + lane) << 3)) = v;
}

// ---------- K1: rmsnorm(x)*n1 -> q(bf16), k(bf16), v(bf16); 256 thr ----------
__global__ __launch_bounds__(256) void k_qkv(
    const float* __restrict__ x, const float* __restrict__ n1,
    const short* __restrict__ wsw,
    short* __restrict__ qbf, short* __restrict__ kbf, short* __restrict__ vbf)
{
    __shared__ short hs[2048];
    const int r0 = blockIdx.x * 16, t = threadIdx.x;
    const int w = t >> 6, lane = t & 63;

    #pragma unroll
    for (int i = 0; i < 4; i++) {
        int r = w * 4 + i;
        const float* xp = x + (size_t)(r0 + r) * 128;
        float v0 = xp[lane], v1 = xp[lane + 64];
        float s = wave_rsum(fmaf(v0, v0, v1 * v1));
        float sc = rsqrtf(s * (1.0f / 128.0f) + EPSF);
        int p3 = (r & 7) << 3;
        hs[r * 128 + (lane ^ p3)]        = f2bs(v0 * sc * n1[lane]);
        hs[r * 128 + ((lane + 64) ^ p3)] = f2bs(v1 * sc * n1[lane + 64]);
    }
    __syncthreads();

    bf16x8 af[4];
    #pragma unroll
    for (int ks = 0; ks < 4; ks++) af[ks] = lda(hs, lane, ks);

    const int rb = (lane >> 4) * 4, cl = lane & 15, cb = w * 32;
    #pragma unroll
    for (int m = 0; m < 3; m++) {
        const short* wb = wsw + (m << 14);
        f32x4 a0 = {0.f,0.f,0.f,0.f}, a1 = {0.f,0.f,0.f,0.f};
        #pragma unroll
        for (int ks = 0; ks < 4; ks++) {
            bf16x8 b0 = *(const bf16x8*)(wb + ((((w * 2) * 4 + ks) * 64 + lane) << 3));
            bf16x8 b1 = *(const bf16x8*)(wb + ((((w * 2 + 1) * 4 + ks) * 64 + lane) << 3));
            a0 = __builtin_amdgcn_mfma_f32_16x16x32_bf16(af[ks], b0, a0, 0, 0, 0);
            a1 = __builtin_amdgcn_mfma_f32_16x16x32_bf16(af[ks], b1, a1, 0, 0, 0);
        }
        short* outp = (m == 0) ? qbf : (m == 1) ? kbf : vbf;
        #pragma unroll
        for (int i = 0; i < 4; i++) {
            outp[(size_t)(r0 + rb + i) * 128 + cb + cl]      = f2bs(a0[i]);
            outp[(size_t)(r0 + rb + i) * 128 + cb + 16 + cl] = f2bs(a1[i]);
        }
    }
}

// ---------- K2: brick attention — branchless QK, K/V share one LDS buffer ----------
__global__ __launch_bounds__(256) void k_attn(
    const short* __restrict__ qbf, const short* __restrict__ kbf,
    const short* __restrict__ vbf, short* __restrict__ obf)
{
    __shared__ short KV_lds[384 * 40];    // 30720 B, holds K then V
    __shared__ int tab[125];

    const int b = blockIdx.x, head = blockIdx.y, t = threadIdx.x;
    const int ow = (b & 3) * 4, oh = ((b >> 2) & 3) * 4, od = (b >> 4) * 2;

    if (t < 125) {
        int dd = t / 25, rem = t % 25;
        tab[t] = dd | ((rem / 5) << 4) | ((rem % 5) << 8);
    }

    // -------- compute staging addresses once; stage K --------
    // thread t handles row t; threads t<128 also handle row t+256
    size_t goff0 = 0, goff1 = 0;
    int sv0 = 0, sv1 = 0;
    {
        int row = t;
        int lw = row & 7, lh = (row >> 3) & 7, ld = row >> 6;
        int gd = od - 2 + ld, gh = oh - 2 + lh, gw_ = ow - 2 + lw;
        sv0 = (((unsigned)gd < 16u) && ((unsigned)gh < 16u) && ((unsigned)gw_ < 16u));
        goff0 = ((size_t)(((gd << 4) | gh) << 4 | gw_)) * 128 + head * 32;
        if (t < 128) {
            int row1 = t + 256;
            int lw1 = row1 & 7, lh1 = (row1 >> 3) & 7, ld1 = row1 >> 6;
            int gd1 = od - 2 + ld1, gh1 = oh - 2 + lh1, gw1 = ow - 2 + lw1;
            sv1 = (((unsigned)gd1 < 16u) && ((unsigned)gh1 < 16u) && ((unsigned)gw1 < 16u));
            goff1 = ((size_t)(((gd1 << 4) | gh1) << 4 | gw1)) * 128 + head * 32;
        }
    }
    {
        uint4 kc[4];
        #pragma unroll
        for (int c2 = 0; c2 < 4; c2++)
            kc[c2] = sv0 ? *(const uint4*)(kbf + goff0 + c2 * 8) : (uint4){0,0,0,0};
        int ro = t * 40, rot = kv_rot(t);
        #pragma unroll
        for (int c2 = 0; c2 < 4; c2++)
            *(uint4*)&KV_lds[ro + ((((c2 + rot) & 3)) << 3)] = kc[c2];
        if (t < 128) {
            uint4 kd[4];
            #pragma unroll
            for (int c2 = 0; c2 < 4; c2++)
                kd[c2] = sv1 ? *(const uint4*)(kbf + goff1 + c2 * 8) : (uint4){0,0,0,0};
            int row1 = t + 256;
            int ro1 = row1 * 40, rot1 = kv_rot(row1);
            #pragma unroll
            for (int c2 = 0; c2 < 4; c2++)
                *(uint4*)&KV_lds[ro1 + ((((c2 + rot1) & 3)) << 3)] = kd[c2];
        }
    }

    const int qi = t >> 3, qt = t & 7;           // 32 queries x 8 lanes
    const int qw_ = qi & 3, qh_ = (qi >> 2) & 3, qd_ = qi >> 4;
    const int gqd = od + qd_, gqh = oh + qh_, gqw = ow + qw_;
    const int gvox = (((gqd << 4) | gqh) << 4) | gqw;
    const int base = (qd_ + 2) * 64 + (qh_ + 2) * 8 + (qw_ + 2);

    // q loads overlap K staging (independent of LDS)
    float qreg[32];
    {
        const float isq = 0.17677669529663687f;  // 1/sqrt(32)
        const short* qp = qbf + (size_t)gvox * 128 + head * 32;
        #pragma unroll
        for (int c2 = 0; c2 < 4; c2++) {
            uint4 raw = *(const uint4*)(qp + c2 * 8);
            const unsigned short* u = (const unsigned short*)&raw;
            #pragma unroll
            for (int j = 0; j < 8; j++) qreg[c2 * 8 + j] = bs2f(u[j]) * isq;
        }
    }
    __syncthreads();

    // -------- branchless QK: precompute (h, valid), then straight-line scores ----
    int hid[16];
    unsigned okbits = 0;
    const int kk0 = qt * 16;
    #pragma unroll
    for (int i = 0; i < 16; i++) {
        int kk = kk0 + i;
        int ttv = tab[(kk < 125) ? kk : 0];
        int dd = (ttv & 15) - 2, dh = ((ttv >> 4) & 15) - 2, dw_ = (ttv >> 8) - 2;
        int ok = (kk < 125)
               & ((unsigned)(gqd + dd) < 16u)
               & ((unsigned)(gqh + dh) < 16u)
               & ((unsigned)(gqw + dw_) < 16u);
        hid[i] = ok ? (base + dd * 64 + dh * 8 + dw_) : 0;
        okbits |= ((unsigned)ok) << i;
    }

    float sc[16];
    float m = -1e30f;
    #pragma unroll
    for (int i = 0; i < 16; i++) {
        int h = hid[i];
        int ro = h * 40, rot = kv_rot(h);
        float acc = 0.f;
        #pragma unroll
        for (int c2 = 0; c2 < 4; c2++) {
            uint4 raw = *(const uint4*)&KV_lds[ro + ((((c2 + rot) & 3)) << 3)];
            const unsigned short* u = (const unsigned short*)&raw;
            #pragma unroll
            for (int j = 0; j < 8; j++) acc = fmaf(qreg[c2 * 8 + j], bs2f(u[j]), acc);
        }
        sc[i] = ((okbits >> i) & 1) ? acc : -1e30f;
        m = fmaxf(m, sc[i]);
    }
    m = fmaxf(m, __shfl_xor(m, 1));
    m = fmaxf(m, __shfl_xor(m, 2));
    m = fmaxf(m, __shfl_xor(m, 4));
    float ssum = 0.f;
    #pragma unroll
    for (int i = 0; i < 16; i++) {
        float p = (sc[i] > -1e29f) ? __expf(sc[i] - m) : 0.f;
        sc[i] = p; ssum += p;
    }
    ssum += __shfl_xor(ssum, 1);
    ssum += __shfl_xor(ssum, 2);
    ssum += __shfl_xor(ssum, 4);
    const float inv = 1.0f / ssum;

    // -------- swap buffer to V (reuse cached addresses) --------
    __syncthreads();   // all QK reads done
    {
        uint4 vc[4];
        #pragma unroll
        for (int c2 = 0; c2 < 4; c2++)
            vc[c2] = sv0 ? *(const uint4*)(vbf + goff0 + c2 * 8) : (uint4){0,0,0,0};
        int ro = t * 40, rot = kv_rot(t);
        #pragma unroll
        for (int c2 = 0; c2 < 4; c2++)
            *(uint4*)&KV_lds[ro + ((((c2 + rot) & 3)) << 3)] = vc[c2];
        if (t < 128) {
            uint4 vd[4];
            #pragma unroll
            for (int c2 = 0; c2 < 4; c2++)
                vd[c2] = sv1 ? *(const uint4*)(vbf + goff1 + c2 * 8) : (uint4){0,0,0,0};
            int row1 = t + 256;
            int ro1 = row1 * 40, rot1 = kv_rot(row1);
            #pragma unroll
            for (int c2 = 0; c2 < 4; c2++)
                *(uint4*)&KV_lds[ro1 + ((((c2 + rot1) & 3)) << 3)] = vd[c2];
        }
    }
    __syncthreads();

    // -------- PV (branchless; p=0 for invalid) --------
    float acc[32];
    #pragma unroll
    for (int c2 = 0; c2 < 32; c2++) acc[c2] = 0.f;
    #pragma unroll
    for (int i = 0; i < 16; i++) {
        float p = sc[i];
        int h = hid[i];
        int ro = h * 40, rot = kv_rot(h);
        #pragma unroll
        for (int c2 = 0; c2 < 4; c2++) {
            uint4 raw = *(const uint4*)&KV_lds[ro + ((((c2 + rot) & 3)) << 3)];
            const unsigned short* u = (const unsigned short*)&raw;
            #pragma unroll
            for (int j = 0; j < 8; j++) acc[c2 * 8 + j] = fmaf(p, bs2f(u[j]), acc[c2 * 8 + j]);
        }
    }
    #pragma unroll
    for (int c2 = 0; c2 < 32; c2++) {
        acc[c2] += __shfl_xor(acc[c2], 1);
        acc[c2] += __shfl_xor(acc[c2], 2);
        acc[c2] += __shfl_xor(acc[c2], 4);
    }
    short o4[4];
    #pragma unroll
    for (int j = 0; j < 4; j++) o4[j] = f2bs(acc[qt * 4 + j] * inv);
    unsigned long long pk; __builtin_memcpy(&pk, o4, 8);
    *(unsigned long long*)&obf[(size_t)gvox * 128 + head * 32 + qt * 4] = pk;
}

// ---------- K3: fused post-chain, 3 barriers (per-wave rmsnorms) ----------
__global__ __launch_bounds__(256) void k_post(
    const short* __restrict__ obf, const short* __restrict__ wsw,
    const float* __restrict__ anw, const float* __restrict__ x,
    const float* __restrict__ n2w, float* __restrict__ out)
{
    __shared__ float ybuf[16][132];
    __shared__ float xres[16][128];
    __shared__ short hs[2048];
    __shared__ short gu[16 * 512];

    const int r0 = blockIdx.x * 16, t = threadIdx.x;
    const int w = t >> 6, lane = t & 63;
    const int ar = lane & 15, ag_ = lane >> 4;

    // phase 1: y = o @ wo
    {
        const short* wb = wsw + (3 << 14);
        f32x4 a0 = {0.f,0.f,0.f,0.f}, a1 = {0.f,0.f,0.f,0.f};
        #pragma unroll
        for (int ks = 0; ks < 4; ks++) {
            bf16x8 a = *(const bf16x8*)(obf + (size_t)(r0 + ar) * 128 + ks * 32 + ag_ * 8);
            bf16x8 b0 = *(const bf16x8*)(wb + ((((w * 2) * 4 + ks) * 64 + lane) << 3));
            bf16x8 b1 = *(const bf16x8*)(wb + ((((w * 2 + 1) * 4 + ks) * 64 + lane) << 3));
            a0 = __builtin_amdgcn_mfma_f32_16x16x32_bf16(a, b0, a0, 0, 0, 0);
            a1 = __builtin_amdgcn_mfma_f32_16x16x32_bf16(a, b1, a1, 0, 0, 0);
        }
        #pragma unroll
        for (int i = 0; i < 4; i++) {
            ybuf[ag_ * 4 + i][w * 32 + ar]      = a0[i];
            ybuf[ag_ * 4 + i][w * 32 + 16 + ar] = a1[i];
        }
    }
    __syncthreads();

    // phase 2+3 fused, per-wave: xres = x + rmsnorm(y)*anw; hs = rmsnorm(xres)*n2w
    #pragma unroll
    for (int i = 0; i < 4; i++) {
        int r = w * 4 + i;
        float y0 = ybuf[r][lane], y1 = ybuf[r][lane + 64];
        float s = wave_rsum(fmaf(y0, y0, y1 * y1));
        float sc = rsqrtf(s * (1.0f / 128.0f) + EPSF);
        const float* xp = x + (size_t)(r0 + r) * 128;
        float xr0 = xp[lane]      + y0 * sc * anw[lane];
        float xr1 = xp[lane + 64] + y1 * sc * anw[lane + 64];
        xres[r][lane] = xr0; xres[r][lane + 64] = xr1;
        float s2 = wave_rsum(fmaf(xr0, xr0, xr1 * xr1));
        float sc2 = rsqrtf(s2 * (1.0f / 128.0f) + EPSF);
        int p3 = (r & 7) << 3;
        hs[r * 128 + (lane ^ p3)]        = f2bs(xr0 * sc2 * n2w[lane]);
        hs[r * 128 + ((lane + 64) ^ p3)] = f2bs(xr1 * sc2 * n2w[lane + 64]);
    }
    __syncthreads();

    // phase 4: gu = silu(h2@gw)*(h2@uw)  (4 waves x 8 col-tiles)
    {
        const short* gwb = wsw + 65536;
        const short* uwb = wsw + 131072;
        bf16x8 af[4];
        #pragma unroll
        for (int ks = 0; ks < 4; ks++) af[ks] = lda(hs, lane, ks);
        f32x4 ag[8], au[8];
        #pragma unroll
        for (int i = 0; i < 8; i++) { ag[i] = (f32x4){0.f,0.f,0.f,0.f}; au[i] = (f32x4){0.f,0.f,0.f,0.f}; }
        #pragma unroll
        for (int ks = 0; ks < 4; ks++) {
            #pragma unroll
            for (int i = 0; i < 8; i++) {
                int ct = w * 8 + i;
                bf16x8 bg = *(const bf16x8*)(gwb + (((ct * 4 + ks) * 64 + lane) << 3));
                bf16x8 bu = *(const bf16x8*)(uwb + (((ct * 4 + ks) * 64 + lane) << 3));
                ag[i] = __builtin_amdgcn_mfma_f32_16x16x32_bf16(af[ks], bg, ag[i], 0, 0, 0);
                au[i] = __builtin_amdgcn_mfma_f32_16x16x32_bf16(af[ks], bu, au[i], 0, 0, 0);
            }
        }
        #pragma unroll
        for (int i = 0; i < 8; i++) {
            int col = (w * 8 + i) * 16 + ar;
            #pragma unroll
            for (int j = 0; j < 4; j++) {
                int row = ag_ * 4 + j;
                float g = ag[i][j], uu = au[i][j];
                float sg = g / (1.0f + __expf(-g));
                gu[row * 512 + (col ^ ((row & 7) << 3))] = f2bs(sg * uu);
            }
        }
    }
    __syncthreads();

    // phase 5: out = xres + gu @ dw (K=512)
    {
        const short* db = wsw + 196608;
        f32x4 a0 = {0.f,0.f,0.f,0.f}, a1 = {0.f,0.f,0.f,0.f};
        #pragma unroll
        for (int ks = 0; ks < 16; ks++) {
            int col = (ks * 32 + ag_ * 8) ^ ((ar & 7) << 3);
            bf16x8 a = *(const bf16x8*)(gu + ar * 512 + col);
            bf16x8 b0 = *(const bf16x8*)(db + ((((w * 2) * 16 + ks) * 64 + lane) << 3));
            bf16x8 b1 = *(const bf16x8*)(db + ((((w * 2 + 1) * 16 + ks) * 64 + lane) << 3));
            a0 = __builtin_amdgcn_mfma_f32_16x16x32_bf16(a, b0, a0, 0, 0, 0);
            a1 = __builtin_amdgcn_mfma_f32_16x16x32_bf16(a, b1, a1, 0, 0, 0);
        }
        #pragma unroll
        for (int i = 0; i < 4; i++) {
            int row = ag_ * 4 + i;
            size_t i0 = (size_t)(r0 + row) * 128 + w * 32 + ar;
            out[i0]      = xres[row][w * 32 + ar]      + a0[i];
            out[i0 + 16] = xres[row][w * 32 + 16 + ar] + a1[i];
        }
    }
}

extern "C" void kernel_launch(void* const* d_in, const int* in_sizes, int n_in,
                              void* d_out, int out_size, void* d_ws, size_t ws_size,
                              hipStream_t stream)
{
    const float* x   = (const float*)d_in[0];
    const float* n1  = (const float*)d_in[1];
    const float* anw = (const float*)d_in[2];
    const float* n2  = (const float*)d_in[3];
    const float* wq  = (const float*)d_in[4];
    const float* wk  = (const float*)d_in[5];
    const float* wv  = (const float*)d_in[6];
    const float* wo  = (const float*)d_in[7];
    const float* gw  = (const float*)d_in[8];
    const float* uw  = (const float*)d_in[9];
    const float* dw  = (const float*)d_in[10];
    float* out = (float*)d_out;

    float* ws = (float*)d_ws;
    short* qbf = (short*)ws;                   // 524288 shorts
    short* kbf = (short*)(ws + 262144);
    short* vbf = (short*)(ws + 524288);
    short* obf = (short*)(ws + 786432);
    short* wsw = (short*)(ws + 1048576);       // 262144 shorts

    k_prep<<<64,  512, 0, stream>>>(wq, wk, wv, wo, gw, uw, dw, wsw);
    k_qkv <<<256, 256, 0, stream>>>(x, n1, wsw, qbf, kbf, vbf);
    dim3 ga(128, 4);
    k_attn<<<ga,  256, 0, stream>>>(qbf, kbf, vbf, obf);
    k_post<<<256, 256, 0, stream>>>(obf, wsw, anw, x, n2, out);
}

// Round 15
// 40.221 us; speedup vs baseline: 4.6724x; 1.0272x over previous
//
#include <hip/hip_runtime.h>
#include <hip/hip_bf16.h>

#define NVOX 4096
#define C    128
#define HID  512
#define EPSF 1e-6f

typedef __attribute__((ext_vector_type(8))) short bf16x8;
typedef __attribute__((ext_vector_type(4))) float f32x4;

__device__ __forceinline__ short f2bs(float f) {
    __hip_bfloat16 h = __float2bfloat16(f);
    short s; __builtin_memcpy(&s, &h, 2); return s;
}
__device__ __forceinline__ float bs2f(unsigned short u) {
    return __uint_as_float(((unsigned)u) << 16);
}

// A-frag from swizzled LDS tile hs[16][128] (bf16 shorts, col ^ ((row&7)<<3))
__device__ __forceinline__ bf16x8 lda(const short* hs, int lane, int ks) {
    int r = lane & 15, g = lane >> 4;
    int col = (ks * 32 + g * 8) ^ ((r & 7) << 3);
    return *(const bf16x8*)(hs + r * 128 + col);
}

__device__ __forceinline__ float wave_rsum(float s) {
    s += __shfl_xor(s, 32); s += __shfl_xor(s, 16); s += __shfl_xor(s, 8);
    s += __shfl_xor(s, 4);  s += __shfl_xor(s, 2);  s += __shfl_xor(s, 1);
    return s;
}

// ---------- weight prep: fp32 -> bf16 fragment-order, coalesced bf16x8 stores ----------
__global__ __launch_bounds__(512) void k_prep(
    const float* __restrict__ wq, const float* __restrict__ wk,
    const float* __restrict__ wv, const float* __restrict__ wo,
    const float* __restrict__ gw, const float* __restrict__ uw,
    const float* __restrict__ dw, short* __restrict__ wsw)
{
    int id = blockIdx.x * 512 + threadIdx.x;   // [0, 32768)
    const float* src; int base, ct, ks, lane, N, KS;
    if (id < 8192) {
        int m = id >> 11, loc = id & 2047;
        src = (m == 0) ? wq : (m == 1) ? wk : (m == 2) ? wv : wo;
        base = m << 14; N = 128; KS = 4;
        ct = loc >> 8; ks = (loc >> 6) & 3; lane = loc & 63;
    } else if (id < 16384) {
        int loc = id - 8192;
        src = gw; base = 65536; N = 512; KS = 4;
        ct = loc >> 8; ks = (loc >> 6) & 3; lane = loc & 63;
    } else if (id < 24576) {
        int loc = id - 16384;
        src = uw; base = 131072; N = 512; KS = 4;
        ct = loc >> 8; ks = (loc >> 6) & 3; lane = loc & 63;
    } else {
        int loc = id - 24576;
        src = dw; base = 196608; N = 128; KS = 16;
        ct = loc >> 10; ks = (loc >> 6) & 15; lane = loc & 63;
    }
    int k0 = ks * 32 + (lane >> 4) * 8;
    int c  = ct * 16 + (lane & 15);
    bf16x8 v;
    #pragma unroll
    for (int j = 0; j < 8; j++) v[j] = f2bs(src[(size_t)(k0 + j) * N + c]);
    *(bf16x8*)(wsw + base + (((ct * KS + ks) * 64 + lane) << 3)) = v;
}

// ---------- K1: rmsnorm(x)*n1 -> q(bf16), k(bf16), v(bf16); 256 thr ----------
__global__ __launch_bounds__(256) void k_qkv(
    const float* __restrict__ x, const float* __restrict__ n1,
    const short* __restrict__ wsw,
    short* __restrict__ qbf, short* __restrict__ kbf, short* __restrict__ vbf)
{
    __shared__ short hs[2048];
    const int r0 = blockIdx.x * 16, t = threadIdx.x;
    const int w = t >> 6, lane = t & 63;

    #pragma unroll
    for (int i = 0; i < 4; i++) {
        int r = w * 4 + i;
        const float* xp = x + (size_t)(r0 + r) * 128;
        float v0 = xp[lane], v1 = xp[lane + 64];
        float s = wave_rsum(fmaf(v0, v0, v1 * v1));
        float sc = rsqrtf(s * (1.0f / 128.0f) + EPSF);
        int p3 = (r & 7) << 3;
        hs[r * 128 + (lane ^ p3)]        = f2bs(v0 * sc * n1[lane]);
        hs[r * 128 + ((lane + 64) ^ p3)] = f2bs(v1 * sc * n1[lane + 64]);
    }
    __syncthreads();

    bf16x8 af[4];
    #pragma unroll
    for (int ks = 0; ks < 4; ks++) af[ks] = lda(hs, lane, ks);

    const int rb = (lane >> 4) * 4, cl = lane & 15, cb = w * 32;
    #pragma unroll
    for (int m = 0; m < 3; m++) {
        const short* wb = wsw + (m << 14);
        f32x4 a0 = {0.f,0.f,0.f,0.f}, a1 = {0.f,0.f,0.f,0.f};
        #pragma unroll
        for (int ks = 0; ks < 4; ks++) {
            bf16x8 b0 = *(const bf16x8*)(wb + ((((w * 2) * 4 + ks) * 64 + lane) << 3));
            bf16x8 b1 = *(const bf16x8*)(wb + ((((w * 2 + 1) * 4 + ks) * 64 + lane) << 3));
            a0 = __builtin_amdgcn_mfma_f32_16x16x32_bf16(af[ks], b0, a0, 0, 0, 0);
            a1 = __builtin_amdgcn_mfma_f32_16x16x32_bf16(af[ks], b1, a1, 0, 0, 0);
        }
        short* outp = (m == 0) ? qbf : (m == 1) ? kbf : vbf;
        #pragma unroll
        for (int i = 0; i < 4; i++) {
            outp[(size_t)(r0 + rb + i) * 128 + cb + cl]      = f2bs(a0[i]);
            outp[(size_t)(r0 + rb + i) * 128 + cb + 16 + cl] = f2bs(a1[i]);
        }
    }
}

// ---------- K2: MFMA brick attention ----------
// block = (brick 4x4x2, head); halo 8x8x6 = 384 rows. 256 thr = 4 waves.
// Phase layout (LDS overlays): [K 30720 | S 30720 | Q 2560 + inv 128] -> [PA | VB | ...]
__global__ __launch_bounds__(256) void k_attn(
    const short* __restrict__ qbf, const short* __restrict__ kbf,
    const short* __restrict__ vbf, short* __restrict__ obf)
{
    __shared__ __align__(16) char smem[64128];
    short* K_lds = (short*)smem;             // [384][40] natural rows (phase 2)
    short* PA    = (short*)smem;             // P in A-frag order (phases 3,5)
    short* S_lds = (short*)(smem + 30720);   // [384][40] bf16 scores (phases 2,3)
    short* VB    = (short*)(smem + 30720);   // V in B-frag order (phases 4,5)
    short* Q_lds = (short*)(smem + 61440);   // [32][40]
    float* inv   = (float*)(smem + 64000);   // [32]

    const int b = blockIdx.x, head = blockIdx.y, t = threadIdx.x;
    const int ow = (b & 3) * 4, oh = ((b >> 2) & 3) * 4, od = (b >> 4) * 2;
    const int w = t >> 6, lane = t & 63;
    const int g = lane >> 4, r = lane & 15;

    // ---- phase 1: stage K (natural rows) + Q; prefetch V rows into registers ----
    uint4 v0[4] = {}, v1[4] = {};
    {
        int row = t;
        int lw = row & 7, lh = (row >> 3) & 7, ld = row >> 6;
        int gd = od - 2 + ld, gh = oh - 2 + lh, gw_ = ow - 2 + lw;
        int sv = (((unsigned)gd < 16u) && ((unsigned)gh < 16u) && ((unsigned)gw_ < 16u));
        size_t off = ((size_t)(((gd << 4) | gh) << 4 | gw_)) * 128 + head * 32;
        uint4 kc[4];
        #pragma unroll
        for (int c2 = 0; c2 < 4; c2++) {
            kc[c2] = sv ? *(const uint4*)(kbf + off + c2 * 8) : (uint4){0,0,0,0};
            v0[c2] = sv ? *(const uint4*)(vbf + off + c2 * 8) : (uint4){0,0,0,0};
        }
        #pragma unroll
        for (int c2 = 0; c2 < 4; c2++) *(uint4*)&K_lds[row * 40 + c2 * 8] = kc[c2];

        if (t < 128) {
            int row1 = t + 256;
            int lw1 = row1 & 7, lh1 = (row1 >> 3) & 7, ld1 = row1 >> 6;
            int gd1 = od - 2 + ld1, gh1 = oh - 2 + lh1, gw1 = ow - 2 + lw1;
            int sv1 = (((unsigned)gd1 < 16u) && ((unsigned)gh1 < 16u) && ((unsigned)gw1 < 16u));
            size_t off1 = ((size_t)(((gd1 << 4) | gh1) << 4 | gw1)) * 128 + head * 32;
            uint4 kd[4];
            #pragma unroll
            for (int c2 = 0; c2 < 4; c2++) {
                kd[c2] = sv1 ? *(const uint4*)(kbf + off1 + c2 * 8) : (uint4){0,0,0,0};
                v1[c2] = sv1 ? *(const uint4*)(vbf + off1 + c2 * 8) : (uint4){0,0,0,0};
            }
            #pragma unroll
            for (int c2 = 0; c2 < 4; c2++) *(uint4*)&K_lds[row1 * 40 + c2 * 8] = kd[c2];

            // Q: q = t>>2, chunk = t&3
            int q = t >> 2, c2q = t & 3;
            int gq = ((od + (q >> 4)) << 8) | ((oh + ((q >> 2) & 3)) << 4) | (ow + (q & 3));
            *(uint4*)&Q_lds[q * 40 + c2q * 8] =
                *(const uint4*)(qbf + (size_t)gq * 128 + head * 32 + c2q * 8);
        }
    }
    __syncthreads();

    // ---- phase 2: S^T[key][q] = K · Q^T  (12 MFMA/wave) ----
    {
        bf16x8 bq0 = *(const bf16x8*)(Q_lds + r * 40 + g * 8);          // queries 0..15
        bf16x8 bq1 = *(const bf16x8*)(Q_lds + (16 + r) * 40 + g * 8);   // queries 16..31
        #pragma unroll
        for (int jj = 0; jj < 6; jj++) {
            int mt = w + jj * 4;                 // key tile
            bf16x8 ak = *(const bf16x8*)(K_lds + (mt * 16 + r) * 40 + g * 8);
            f32x4 a0 = {0.f,0.f,0.f,0.f}, a1 = {0.f,0.f,0.f,0.f};
            a0 = __builtin_amdgcn_mfma_f32_16x16x32_bf16(ak, bq0, a0, 0, 0, 0);
            a1 = __builtin_amdgcn_mfma_f32_16x16x32_bf16(ak, bq1, a1, 0, 0, 0);
            #pragma unroll
            for (int i = 0; i < 4; i++) {
                int key = mt * 16 + g * 4 + i;
                S_lds[key * 40 + r]      = f2bs(a0[i]);
                S_lds[key * 40 + 16 + r] = f2bs(a1[i]);
            }
        }
    }
    __syncthreads();

    // ---- phase 3: masked softmax per query; write P (unnormalized) in A-frag order ----
    {
        const int q = t >> 3, kl = t & 7;
        const int qw_ = q & 3, qh_ = (q >> 2) & 3, qd_ = q >> 4;
        const float isq = 0.17677669529663687f;   // 1/sqrt(32)
        float mx = -1e30f;
        #pragma unroll
        for (int j = 0; j < 48; j++) {
            int k = kl + (j << 3);
            int lw = k & 7, lh = (k >> 3) & 7, ld = k >> 6;
            int ok = ((unsigned)(ld - qd_) <= 4u) & ((unsigned)(lh - qh_) <= 4u)
                   & ((unsigned)(lw - qw_) <= 4u)
                   & ((unsigned)(od - 2 + ld) < 16u) & ((unsigned)(oh - 2 + lh) < 16u)
                   & ((unsigned)(ow - 2 + lw) < 16u);
            float s = bs2f((unsigned short)S_lds[k * 40 + q]) * isq;
            mx = ok ? fmaxf(mx, s) : mx;
        }
        mx = fmaxf(mx, __shfl_xor(mx, 1));
        mx = fmaxf(mx, __shfl_xor(mx, 2));
        mx = fmaxf(mx, __shfl_xor(mx, 4));
        float ssum = 0.f;
        const int pabase = (q >> 4) * 12 * 512 + (q & 15) * 8 + kl;
        #pragma unroll
        for (int j = 0; j < 48; j++) {
            int k = kl + (j << 3);
            int lw = k & 7, lh = (k >> 3) & 7, ld = k >> 6;
            int ok = ((unsigned)(ld - qd_) <= 4u) & ((unsigned)(lh - qh_) <= 4u)
                   & ((unsigned)(lw - qw_) <= 4u)
                   & ((unsigned)(od - 2 + ld) < 16u) & ((unsigned)(oh - 2 + lh) < 16u)
                   & ((unsigned)(ow - 2 + lw) < 16u);
            float s = bs2f((unsigned short)S_lds[k * 40 + q]) * isq;
            float p = ok ? __expf(s - mx) : 0.f;
            ssum += p;
            PA[pabase + (j >> 2) * 512 + (j & 3) * 128] = f2bs(p);
        }
        ssum += __shfl_xor(ssum, 1);
        ssum += __shfl_xor(ssum, 2);
        ssum += __shfl_xor(ssum, 4);
        if (kl == 0) inv[q] = 1.0f / ssum;
    }
    __syncthreads();

    // ---- phase 4: write V rows (from registers) into B-frag order ----
    {
        int row = t;
        int ks = row >> 5, g3 = (row >> 3) & 3, j3 = row & 7;
        const unsigned short* u = (const unsigned short*)v0;
        #pragma unroll
        for (int c = 0; c < 32; c++)
            VB[((c >> 4) * 12 + ks) * 512 + g3 * 128 + (c & 15) * 8 + j3] = (short)u[c];
        if (t < 128) {
            int row1 = t + 256;
            int ks1 = row1 >> 5, g31 = (row1 >> 3) & 3, j31 = row1 & 7;
            const unsigned short* u1 = (const unsigned short*)v1;
            #pragma unroll
            for (int c = 0; c < 32; c++)
                VB[((c >> 4) * 12 + ks1) * 512 + g31 * 128 + (c & 15) * 8 + j31] = (short)u1[c];
        }
    }
    __syncthreads();

    // ---- phase 5: O[q][c] = P · V  (12 MFMA/wave, one output tile per wave) ----
    {
        const int mt2 = w >> 1, ct = w & 1;
        f32x4 acc = {0.f,0.f,0.f,0.f};
        #pragma unroll
        for (int ks = 0; ks < 12; ks++) {
            bf16x8 pa = *(const bf16x8*)(PA + (((mt2 * 12 + ks) * 64 + lane) << 3));
            bf16x8 vb = *(const bf16x8*)(VB + (((ct * 12 + ks) * 64 + lane) << 3));
            acc = __builtin_amdgcn_mfma_f32_16x16x32_bf16(pa, vb, acc, 0, 0, 0);
        }
        #pragma unroll
        for (int i = 0; i < 4; i++) {
            int q = mt2 * 16 + g * 4 + i;
            int c = ct * 16 + r;
            int gvox = ((od + (q >> 4)) << 8) | ((oh + ((q >> 2) & 3)) << 4) | (ow + (q & 3));
            obf[(size_t)gvox * 128 + head * 32 + c] = f2bs(acc[i] * inv[q]);
        }
    }
}

// ---------- K3: fused post-chain, 3 barriers (per-wave rmsnorms) ----------
__global__ __launch_bounds__(256) void k_post(
    const short* __restrict__ obf, const short* __restrict__ wsw,
    const float* __restrict__ anw, const float* __restrict__ x,
    const float* __restrict__ n2w, float* __restrict__ out)
{
    __shared__ float ybuf[16][132];
    __shared__ float xres[16][128];
    __shared__ short hs[2048];
    __shared__ short gu[16 * 512];

    const int r0 = blockIdx.x * 16, t = threadIdx.x;
    const int w = t >> 6, lane = t & 63;
    const int ar = lane & 15, ag_ = lane >> 4;

    // phase 1: y = o @ wo
    {
        const short* wb = wsw + (3 << 14);
        f32x4 a0 = {0.f,0.f,0.f,0.f}, a1 = {0.f,0.f,0.f,0.f};
        #pragma unroll
        for (int ks = 0; ks < 4; ks++) {
            bf16x8 a = *(const bf16x8*)(obf + (size_t)(r0 + ar) * 128 + ks * 32 + ag_ * 8);
            bf16x8 b0 = *(const bf16x8*)(wb + ((((w * 2) * 4 + ks) * 64 + lane) << 3));
            bf16x8 b1 = *(const bf16x8*)(wb + ((((w * 2 + 1) * 4 + ks) * 64 + lane) << 3));
            a0 = __builtin_amdgcn_mfma_f32_16x16x32_bf16(a, b0, a0, 0, 0, 0);
            a1 = __builtin_amdgcn_mfma_f32_16x16x32_bf16(a, b1, a1, 0, 0, 0);
        }
        #pragma unroll
        for (int i = 0; i < 4; i++) {
            ybuf[ag_ * 4 + i][w * 32 + ar]      = a0[i];
            ybuf[ag_ * 4 + i][w * 32 + 16 + ar] = a1[i];
        }
    }
    __syncthreads();

    // phase 2+3 fused, per-wave: xres = x + rmsnorm(y)*anw; hs = rmsnorm(xres)*n2w
    #pragma unroll
    for (int i = 0; i < 4; i++) {
        int r = w * 4 + i;
        float y0 = ybuf[r][lane], y1 = ybuf[r][lane + 64];
        float s = wave_rsum(fmaf(y0, y0, y1 * y1));
        float sc = rsqrtf(s * (1.0f / 128.0f) + EPSF);
        const float* xp = x + (size_t)(r0 + r) * 128;
        float xr0 = xp[lane]      + y0 * sc * anw[lane];
        float xr1 = xp[lane + 64] + y1 * sc * anw[lane + 64];
        xres[r][lane] = xr0; xres[r][lane + 64] = xr1;
        float s2 = wave_rsum(fmaf(xr0, xr0, xr1 * xr1));
        float sc2 = rsqrtf(s2 * (1.0f / 128.0f) + EPSF);
        int p3 = (r & 7) << 3;
        hs[r * 128 + (lane ^ p3)]        = f2bs(xr0 * sc2 * n2w[lane]);
        hs[r * 128 + ((lane + 64) ^ p3)] = f2bs(xr1 * sc2 * n2w[lane + 64]);
    }
    __syncthreads();

    // phase 4: gu = silu(h2@gw)*(h2@uw)  (4 waves x 8 col-tiles)
    {
        const short* gwb = wsw + 65536;
        const short* uwb = wsw + 131072;
        bf16x8 af[4];
        #pragma unroll
        for (int ks = 0; ks < 4; ks++) af[ks] = lda(hs, lane, ks);
        f32x4 ag[8], au[8];
        #pragma unroll
        for (int i = 0; i < 8; i++) { ag[i] = (f32x4){0.f,0.f,0.f,0.f}; au[i] = (f32x4){0.f,0.f,0.f,0.f}; }
        #pragma unroll
        for (int ks = 0; ks < 4; ks++) {
            #pragma unroll
            for (int i = 0; i < 8; i++) {
                int ct = w * 8 + i;
                bf16x8 bg = *(const bf16x8*)(gwb + (((ct * 4 + ks) * 64 + lane) << 3));
                bf16x8 bu = *(const bf16x8*)(uwb + (((ct * 4 + ks) * 64 + lane) << 3));
                ag[i] = __builtin_amdgcn_mfma_f32_16x16x32_bf16(af[ks], bg, ag[i], 0, 0, 0);
                au[i] = __builtin_amdgcn_mfma_f32_16x16x32_bf16(af[ks], bu, au[i], 0, 0, 0);
            }
        }
        #pragma unroll
        for (int i = 0; i < 8; i++) {
            int col = (w * 8 + i) * 16 + ar;
            #pragma unroll
            for (int j = 0; j < 4; j++) {
                int row = ag_ * 4 + j;
                float g = ag[i][j], uu = au[i][j];
                float sg = g / (1.0f + __expf(-g));
                gu[row * 512 + (col ^ ((row & 7) << 3))] = f2bs(sg * uu);
            }
        }
    }
    __syncthreads();

    // phase 5: out = xres + gu @ dw (K=512)
    {
        const short* db = wsw + 196608;
        f32x4 a0 = {0.f,0.f,0.f,0.f}, a1 = {0.f,0.f,0.f,0.f};
        #pragma unroll
        for (int ks = 0; ks < 16; ks++) {
            int col = (ks * 32 + ag_ * 8) ^ ((ar & 7) << 3);
            bf16x8 a = *(const bf16x8*)(gu + ar * 512 + col);
            bf16x8 b0 = *(const bf16x8*)(db + ((((w * 2) * 16 + ks) * 64 + lane) << 3));
            bf16x8 b1 = *(const bf16x8*)(db + ((((w * 2 + 1) * 16 + ks) * 64 + lane) << 3));
            a0 = __builtin_amdgcn_mfma_f32_16x16x32_bf16(a, b0, a0, 0, 0, 0);
            a1 = __builtin_amdgcn_mfma_f32_16x16x32_bf16(a, b1, a1, 0, 0, 0);
        }
        #pragma unroll
        for (int i = 0; i < 4; i++) {
            int row = ag_ * 4 + i;
            size_t i0 = (size_t)(r0 + row) * 128 + w * 32 + ar;
            out[i0]      = xres[row][w * 32 + ar]      + a0[i];
            out[i0 + 16] = xres[row][w * 32 + 16 + ar] + a1[i];
        }
    }
}

extern "C" void kernel_launch(void* const* d_in, const int* in_sizes, int n_in,
                              void* d_out, int out_size, void* d_ws, size_t ws_size,
                              hipStream_t stream)
{
    const float* x   = (const float*)d_in[0];
    const float* n1  = (const float*)d_in[1];
    const float* anw = (const float*)d_in[2];
    const float* n2  = (const float*)d_in[3];
    const float* wq  = (const float*)d_in[4];
    const float* wk  = (const float*)d_in[5];
    const float* wv  = (const float*)d_in[6];
    const float* wo  = (const float*)d_in[7];
    const float* gw  = (const float*)d_in[8];
    const float* uw  = (const float*)d_in[9];
    const float* dw  = (const float*)d_in[10];
    float* out = (float*)d_out;

    float* ws = (float*)d_ws;
    short* qbf = (short*)ws;                   // 524288 shorts
    short* kbf = (short*)(ws + 262144);
    short* vbf = (short*)(ws + 524288);
    short* obf = (short*)(ws + 786432);
    short* wsw = (short*)(ws + 1048576);       // 262144 shorts

    k_prep<<<64,  512, 0, stream>>>(wq, wk, wv, wo, gw, uw, dw, wsw);
    k_qkv <<<256, 256, 0, stream>>>(x, n1, wsw, qbf, kbf, vbf);
    dim3 ga(128, 4);
    k_attn<<<ga,  256, 0, stream>>>(qbf, kbf, vbf, obf);
    k_post<<<256, 256, 0, stream>>>(obf, wsw, anw, x, n2, out);
}

// Round 16
// 37.498 us; speedup vs baseline: 5.0116x; 1.0726x over previous
//
#include <hip/hip_runtime.h>
#include <hip/hip_bf16.h>

#define NVOX 4096
#define C    128
#define HID  512
#define EPSF 1e-6f

typedef __attribute__((ext_vector_type(8))) short bf16x8;
typedef __attribute__((ext_vector_type(4))) float f32x4;

__device__ __forceinline__ short f2bs(float f) {
    __hip_bfloat16 h = __float2bfloat16(f);
    short s; __builtin_memcpy(&s, &h, 2); return s;
}
__device__ __forceinline__ float bs2f(unsigned short u) {
    return __uint_as_float(((unsigned)u) << 16);
}

// A-frag from swizzled LDS tile hs[16][128] (bf16 shorts, col ^ ((row&7)<<3))
__device__ __forceinline__ bf16x8 lda(const short* hs, int lane, int ks) {
    int r = lane & 15, g = lane >> 4;
    int col = (ks * 32 + g * 8) ^ ((r & 7) << 3);
    return *(const bf16x8*)(hs + r * 128 + col);
}

__device__ __forceinline__ float wave_rsum(float s) {
    s += __shfl_xor(s, 32); s += __shfl_xor(s, 16); s += __shfl_xor(s, 8);
    s += __shfl_xor(s, 4);  s += __shfl_xor(s, 2);  s += __shfl_xor(s, 1);
    return s;
}

// ---------- weight prep: fp32 -> bf16 fragment-order, coalesced bf16x8 stores ----------
__global__ __launch_bounds__(512) void k_prep(
    const float* __restrict__ wq, const float* __restrict__ wk,
    const float* __restrict__ wv, const float* __restrict__ wo,
    const float* __restrict__ gw, const float* __restrict__ uw,
    const float* __restrict__ dw, short* __restrict__ wsw)
{
    int id = blockIdx.x * 512 + threadIdx.x;   // [0, 32768)
    const float* src; int base, ct, ks, lane, N, KS;
    if (id < 8192) {
        int m = id >> 11, loc = id & 2047;
        src = (m == 0) ? wq : (m == 1) ? wk : (m == 2) ? wv : wo;
        base = m << 14; N = 128; KS = 4;
        ct = loc >> 8; ks = (loc >> 6) & 3; lane = loc & 63;
    } else if (id < 16384) {
        int loc = id - 8192;
        src = gw; base = 65536; N = 512; KS = 4;
        ct = loc >> 8; ks = (loc >> 6) & 3; lane = loc & 63;
    } else if (id < 24576) {
        int loc = id - 16384;
        src = uw; base = 131072; N = 512; KS = 4;
        ct = loc >> 8; ks = (loc >> 6) & 3; lane = loc & 63;
    } else {
        int loc = id - 24576;
        src = dw; base = 196608; N = 128; KS = 16;
        ct = loc >> 10; ks = (loc >> 6) & 15; lane = loc & 63;
    }
    int k0 = ks * 32 + (lane >> 4) * 8;
    int c  = ct * 16 + (lane & 15);
    bf16x8 v;
    #pragma unroll
    for (int j = 0; j < 8; j++) v[j] = f2bs(src[(size_t)(k0 + j) * N + c]);
    *(bf16x8*)(wsw + base + (((ct * KS + ks) * 64 + lane) << 3)) = v;
}

// ---------- K1: rmsnorm(x)*n1 -> q,k,v (bf16, HEAD-MAJOR [head][4096][32]) ----------
__global__ __launch_bounds__(256) void k_qkv(
    const float* __restrict__ x, const float* __restrict__ n1,
    const short* __restrict__ wsw,
    short* __restrict__ qbf, short* __restrict__ kbf, short* __restrict__ vbf)
{
    __shared__ short hs[2048];
    const int r0 = blockIdx.x * 16, t = threadIdx.x;
    const int w = t >> 6, lane = t & 63;

    #pragma unroll
    for (int i = 0; i < 4; i++) {
        int r = w * 4 + i;
        const float* xp = x + (size_t)(r0 + r) * 128;
        float v0 = xp[lane], v1 = xp[lane + 64];
        float s = wave_rsum(fmaf(v0, v0, v1 * v1));
        float sc = rsqrtf(s * (1.0f / 128.0f) + EPSF);
        int p3 = (r & 7) << 3;
        hs[r * 128 + (lane ^ p3)]        = f2bs(v0 * sc * n1[lane]);
        hs[r * 128 + ((lane + 64) ^ p3)] = f2bs(v1 * sc * n1[lane + 64]);
    }
    __syncthreads();

    bf16x8 af[4];
    #pragma unroll
    for (int ks = 0; ks < 4; ks++) af[ks] = lda(hs, lane, ks);

    const int rb = (lane >> 4) * 4, cl = lane & 15;
    #pragma unroll
    for (int m = 0; m < 3; m++) {
        const short* wb = wsw + (m << 14);
        f32x4 a0 = {0.f,0.f,0.f,0.f}, a1 = {0.f,0.f,0.f,0.f};
        #pragma unroll
        for (int ks = 0; ks < 4; ks++) {
            bf16x8 b0 = *(const bf16x8*)(wb + ((((w * 2) * 4 + ks) * 64 + lane) << 3));
            bf16x8 b1 = *(const bf16x8*)(wb + ((((w * 2 + 1) * 4 + ks) * 64 + lane) << 3));
            a0 = __builtin_amdgcn_mfma_f32_16x16x32_bf16(af[ks], b0, a0, 0, 0, 0);
            a1 = __builtin_amdgcn_mfma_f32_16x16x32_bf16(af[ks], b1, a1, 0, 0, 0);
        }
        short* outp = (m == 0) ? qbf : (m == 1) ? kbf : vbf;
        short* hp = outp + (size_t)w * NVOX * 32;    // wave w == head w
        #pragma unroll
        for (int i = 0; i < 4; i++) {
            hp[(size_t)(r0 + rb + i) * 32 + cl]      = f2bs(a0[i]);
            hp[(size_t)(r0 + rb + i) * 32 + 16 + cl] = f2bs(a1[i]);
        }
    }
}

// ---------- K2: MFMA brick attention (head-major inputs, coalesced staging) ----------
// block = (brick 4x4x2, head); halo 8x8x6 = 384 rows. 256 thr = 4 waves.
// LDS overlays: [K 30720 | S 30720 | Q 2560 + inv 128] -> [PA | VB | ...]
__global__ __launch_bounds__(256) void k_attn(
    const short* __restrict__ qbf, const short* __restrict__ kbf,
    const short* __restrict__ vbf, short* __restrict__ obf)
{
    __shared__ __align__(16) char smem[64128];
    short* K_lds = (short*)smem;             // [384][40] natural rows (phase 2)
    short* PA    = (short*)smem;             // P in A-frag order (phases 3,5)
    short* S_lds = (short*)(smem + 30720);   // [384][40] bf16 scores (phases 2,3)
    short* VB    = (short*)(smem + 30720);   // V in B-frag order (phases 4,5)
    short* Q_lds = (short*)(smem + 61440);   // [32][40]
    float* inv   = (float*)(smem + 64000);   // [32]

    const int b = blockIdx.x, head = blockIdx.y, t = threadIdx.x;
    const int ow = (b & 3) * 4, oh = ((b >> 2) & 3) * 4, od = (b >> 4) * 2;
    const int w = t >> 6, lane = t & 63;
    const int g = lane >> 4, r = lane & 15;
    const short* kh = kbf + (size_t)head * NVOX * 32;
    const short* vh = vbf + (size_t)head * NVOX * 32;
    const short* qh = qbf + (size_t)head * NVOX * 32;

    // ---- phase 1: stage K + Q; prefetch V rows into registers ----
    // rows 0..255 -> thread t; rows 256..383 -> threads 128..255; Q -> threads 0..127
    uint4 v0[4] = {}, v1[4] = {};
    {
        int row = t;
        int lw = row & 7, lh = (row >> 3) & 7, ld = row >> 6;
        int gd = od - 2 + ld, gh = oh - 2 + lh, gw_ = ow - 2 + lw;
        int sv = (((unsigned)gd < 16u) && ((unsigned)gh < 16u) && ((unsigned)gw_ < 16u));
        size_t off = (size_t)((((gd << 4) | gh) << 4) | gw_) * 32;
        uint4 kc[4];
        #pragma unroll
        for (int c2 = 0; c2 < 4; c2++) {
            kc[c2] = sv ? *(const uint4*)(kh + off + c2 * 8) : (uint4){0,0,0,0};
            v0[c2] = sv ? *(const uint4*)(vh + off + c2 * 8) : (uint4){0,0,0,0};
        }
        #pragma unroll
        for (int c2 = 0; c2 < 4; c2++) *(uint4*)&K_lds[row * 40 + c2 * 8] = kc[c2];

        if (t >= 128) {
            int row1 = t + 128;   // 256..383
            int lw1 = row1 & 7, lh1 = (row1 >> 3) & 7, ld1 = row1 >> 6;
            int gd1 = od - 2 + ld1, gh1 = oh - 2 + lh1, gw1 = ow - 2 + lw1;
            int sv1 = (((unsigned)gd1 < 16u) && ((unsigned)gh1 < 16u) && ((unsigned)gw1 < 16u));
            size_t off1 = (size_t)((((gd1 << 4) | gh1) << 4) | gw1) * 32;
            uint4 kd[4];
            #pragma unroll
            for (int c2 = 0; c2 < 4; c2++) {
                kd[c2] = sv1 ? *(const uint4*)(kh + off1 + c2 * 8) : (uint4){0,0,0,0};
                v1[c2] = sv1 ? *(const uint4*)(vh + off1 + c2 * 8) : (uint4){0,0,0,0};
            }
            #pragma unroll
            for (int c2 = 0; c2 < 4; c2++) *(uint4*)&K_lds[row1 * 40 + c2 * 8] = kd[c2];
        } else {
            int q = t >> 2, c2q = t & 3;
            int gq = ((od + (q >> 4)) << 8) | ((oh + ((q >> 2) & 3)) << 4) | (ow + (q & 3));
            *(uint4*)&Q_lds[q * 40 + c2q * 8] = *(const uint4*)(qh + (size_t)gq * 32 + c2q * 8);
        }
    }
    __syncthreads();

    // ---- phase 2: S^T[key][q] = K · Q^T  (12 MFMA/wave) ----
    {
        bf16x8 bq0 = *(const bf16x8*)(Q_lds + r * 40 + g * 8);          // queries 0..15
        bf16x8 bq1 = *(const bf16x8*)(Q_lds + (16 + r) * 40 + g * 8);   // queries 16..31
        #pragma unroll
        for (int jj = 0; jj < 6; jj++) {
            int mt = w + jj * 4;                 // key tile
            bf16x8 ak = *(const bf16x8*)(K_lds + (mt * 16 + r) * 40 + g * 8);
            f32x4 a0 = {0.f,0.f,0.f,0.f}, a1 = {0.f,0.f,0.f,0.f};
            a0 = __builtin_amdgcn_mfma_f32_16x16x32_bf16(ak, bq0, a0, 0, 0, 0);
            a1 = __builtin_amdgcn_mfma_f32_16x16x32_bf16(ak, bq1, a1, 0, 0, 0);
            #pragma unroll
            for (int i = 0; i < 4; i++) {
                int key = mt * 16 + g * 4 + i;
                S_lds[key * 40 + r]      = f2bs(a0[i]);
                S_lds[key * 40 + 16 + r] = f2bs(a1[i]);
            }
        }
    }
    __syncthreads();

    // ---- phase 3: masked softmax per query; write P (unnormalized) in A-frag order ----
    {
        const int q = t >> 3, kl = t & 7;
        const int qw_ = q & 3, qh_ = (q >> 2) & 3, qd_ = q >> 4;
        const float isq = 0.17677669529663687f;   // 1/sqrt(32)
        float mx = -1e30f;
        #pragma unroll
        for (int j = 0; j < 48; j++) {
            int k = kl + (j << 3);
            int lw = k & 7, lh = (k >> 3) & 7, ld = k >> 6;
            int ok = ((unsigned)(ld - qd_) <= 4u) & ((unsigned)(lh - qh_) <= 4u)
                   & ((unsigned)(lw - qw_) <= 4u)
                   & ((unsigned)(od - 2 + ld) < 16u) & ((unsigned)(oh - 2 + lh) < 16u)
                   & ((unsigned)(ow - 2 + lw) < 16u);
            float s = bs2f((unsigned short)S_lds[k * 40 + q]) * isq;
            mx = ok ? fmaxf(mx, s) : mx;
        }
        mx = fmaxf(mx, __shfl_xor(mx, 1));
        mx = fmaxf(mx, __shfl_xor(mx, 2));
        mx = fmaxf(mx, __shfl_xor(mx, 4));
        float ssum = 0.f;
        const int pabase = (q >> 4) * 12 * 512 + (q & 15) * 8 + kl;
        #pragma unroll
        for (int j = 0; j < 48; j++) {
            int k = kl + (j << 3);
            int lw = k & 7, lh = (k >> 3) & 7, ld = k >> 6;
            int ok = ((unsigned)(ld - qd_) <= 4u) & ((unsigned)(lh - qh_) <= 4u)
                   & ((unsigned)(lw - qw_) <= 4u)
                   & ((unsigned)(od - 2 + ld) < 16u) & ((unsigned)(oh - 2 + lh) < 16u)
                   & ((unsigned)(ow - 2 + lw) < 16u);
            float s = bs2f((unsigned short)S_lds[k * 40 + q]) * isq;
            float p = ok ? __expf(s - mx) : 0.f;
            ssum += p;
            PA[pabase + (j >> 2) * 512 + (j & 3) * 128] = f2bs(p);
        }
        ssum += __shfl_xor(ssum, 1);
        ssum += __shfl_xor(ssum, 2);
        ssum += __shfl_xor(ssum, 4);
        if (kl == 0) inv[q] = 1.0f / ssum;
    }
    __syncthreads();

    // ---- phase 4: write V rows (from registers) into B-frag order ----
    {
        int row = t;
        int ks = row >> 5, g3 = (row >> 3) & 3, j3 = row & 7;
        const unsigned short* u = (const unsigned short*)v0;
        #pragma unroll
        for (int c = 0; c < 32; c++)
            VB[((c >> 4) * 12 + ks) * 512 + g3 * 128 + (c & 15) * 8 + j3] = (short)u[c];
        if (t >= 128) {
            int row1 = t + 128;
            int ks1 = row1 >> 5, g31 = (row1 >> 3) & 3, j31 = row1 & 7;
            const unsigned short* u1 = (const unsigned short*)v1;
            #pragma unroll
            for (int c = 0; c < 32; c++)
                VB[((c >> 4) * 12 + ks1) * 512 + g31 * 128 + (c & 15) * 8 + j31] = (short)u1[c];
        }
    }
    __syncthreads();

    // ---- phase 5: O[q][c] = P · V  (12 MFMA/wave, one output tile per wave) ----
    {
        const int mt2 = w >> 1, ct = w & 1;
        f32x4 acc = {0.f,0.f,0.f,0.f};
        #pragma unroll
        for (int ks = 0; ks < 12; ks++) {
            bf16x8 pa = *(const bf16x8*)(PA + (((mt2 * 12 + ks) * 64 + lane) << 3));
            bf16x8 vb = *(const bf16x8*)(VB + (((ct * 12 + ks) * 64 + lane) << 3));
            acc = __builtin_amdgcn_mfma_f32_16x16x32_bf16(pa, vb, acc, 0, 0, 0);
        }
        #pragma unroll
        for (int i = 0; i < 4; i++) {
            int q = mt2 * 16 + g * 4 + i;
            int c = ct * 16 + r;
            int gvox = ((od + (q >> 4)) << 8) | ((oh + ((q >> 2) & 3)) << 4) | (ow + (q & 3));
            obf[(size_t)gvox * 128 + head * 32 + c] = f2bs(acc[i] * inv[q]);
        }
    }
}

// ---------- K3: fused post-chain, 3 barriers (per-wave rmsnorms) ----------
__global__ __launch_bounds__(256) void k_post(
    const short* __restrict__ obf, const short* __restrict__ wsw,
    const float* __restrict__ anw, const float* __restrict__ x,
    const float* __restrict__ n2w, float* __restrict__ out)
{
    __shared__ float ybuf[16][132];
    __shared__ float xres[16][128];
    __shared__ short hs[2048];
    __shared__ short gu[16 * 512];

    const int r0 = blockIdx.x * 16, t = threadIdx.x;
    const int w = t >> 6, lane = t & 63;
    const int ar = lane & 15, ag_ = lane >> 4;

    // phase 1: y = o @ wo
    {
        const short* wb = wsw + (3 << 14);
        f32x4 a0 = {0.f,0.f,0.f,0.f}, a1 = {0.f,0.f,0.f,0.f};
        #pragma unroll
        for (int ks = 0; ks < 4; ks++) {
            bf16x8 a = *(const bf16x8*)(obf + (size_t)(r0 + ar) * 128 + ks * 32 + ag_ * 8);
            bf16x8 b0 = *(const bf16x8*)(wb + ((((w * 2) * 4 + ks) * 64 + lane) << 3));
            bf16x8 b1 = *(const bf16x8*)(wb + ((((w * 2 + 1) * 4 + ks) * 64 + lane) << 3));
            a0 = __builtin_amdgcn_mfma_f32_16x16x32_bf16(a, b0, a0, 0, 0, 0);
            a1 = __builtin_amdgcn_mfma_f32_16x16x32_bf16(a, b1, a1, 0, 0, 0);
        }
        #pragma unroll
        for (int i = 0; i < 4; i++) {
            ybuf[ag_ * 4 + i][w * 32 + ar]      = a0[i];
            ybuf[ag_ * 4 + i][w * 32 + 16 + ar] = a1[i];
        }
    }
    __syncthreads();

    // phase 2+3 fused, per-wave: xres = x + rmsnorm(y)*anw; hs = rmsnorm(xres)*n2w
    #pragma unroll
    for (int i = 0; i < 4; i++) {
        int r = w * 4 + i;
        float y0 = ybuf[r][lane], y1 = ybuf[r][lane + 64];
        float s = wave_rsum(fmaf(y0, y0, y1 * y1));
        float sc = rsqrtf(s * (1.0f / 128.0f) + EPSF);
        const float* xp = x + (size_t)(r0 + r) * 128;
        float xr0 = xp[lane]      + y0 * sc * anw[lane];
        float xr1 = xp[lane + 64] + y1 * sc * anw[lane + 64];
        xres[r][lane] = xr0; xres[r][lane + 64] = xr1;
        float s2 = wave_rsum(fmaf(xr0, xr0, xr1 * xr1));
        float sc2 = rsqrtf(s2 * (1.0f / 128.0f) + EPSF);
        int p3 = (r & 7) << 3;
        hs[r * 128 + (lane ^ p3)]        = f2bs(xr0 * sc2 * n2w[lane]);
        hs[r * 128 + ((lane + 64) ^ p3)] = f2bs(xr1 * sc2 * n2w[lane + 64]);
    }
    __syncthreads();

    // phase 4: gu = silu(h2@gw)*(h2@uw)  (4 waves x 8 col-tiles)
    {
        const short* gwb = wsw + 65536;
        const short* uwb = wsw + 131072;
        bf16x8 af[4];
        #pragma unroll
        for (int ks = 0; ks < 4; ks++) af[ks] = lda(hs, lane, ks);
        f32x4 ag[8], au[8];
        #pragma unroll
        for (int i = 0; i < 8; i++) { ag[i] = (f32x4){0.f,0.f,0.f,0.f}; au[i] = (f32x4){0.f,0.f,0.f,0.f}; }
        #pragma unroll
        for (int ks = 0; ks < 4; ks++) {
            #pragma unroll
            for (int i = 0; i < 8; i++) {
                int ct = w * 8 + i;
                bf16x8 bg = *(const bf16x8*)(gwb + (((ct * 4 + ks) * 64 + lane) << 3));
                bf16x8 bu = *(const bf16x8*)(uwb + (((ct * 4 + ks) * 64 + lane) << 3));
                ag[i] = __builtin_amdgcn_mfma_f32_16x16x32_bf16(af[ks], bg, ag[i], 0, 0, 0);
                au[i] = __builtin_amdgcn_mfma_f32_16x16x32_bf16(af[ks], bu, au[i], 0, 0, 0);
            }
        }
        #pragma unroll
        for (int i = 0; i < 8; i++) {
            int col = (w * 8 + i) * 16 + ar;
            #pragma unroll
            for (int j = 0; j < 4; j++) {
                int row = ag_ * 4 + j;
                float g = ag[i][j], uu = au[i][j];
                float sg = g / (1.0f + __expf(-g));
                gu[row * 512 + (col ^ ((row & 7) << 3))] = f2bs(sg * uu);
            }
        }
    }
    __syncthreads();

    // phase 5: out = xres + gu @ dw (K=512)
    {
        const short* db = wsw + 196608;
        f32x4 a0 = {0.f,0.f,0.f,0.f}, a1 = {0.f,0.f,0.f,0.f};
        #pragma unroll
        for (int ks = 0; ks < 16; ks++) {
            int col = (ks * 32 + ag_ * 8) ^ ((ar & 7) << 3);
            bf16x8 a = *(const bf16x8*)(gu + ar * 512 + col);
            bf16x8 b0 = *(const bf16x8*)(db + ((((w * 2) * 16 + ks) * 64 + lane) << 3));
            bf16x8 b1 = *(const bf16x8*)(db + ((((w * 2 + 1) * 16 + ks) * 64 + lane) << 3));
            a0 = __builtin_amdgcn_mfma_f32_16x16x32_bf16(a, b0, a0, 0, 0, 0);
            a1 = __builtin_amdgcn_mfma_f32_16x16x32_bf16(a, b1, a1, 0, 0, 0);
        }
        #pragma unroll
        for (int i = 0; i < 4; i++) {
            int row = ag_ * 4 + i;
            size_t i0 = (size_t)(r0 + row) * 128 + w * 32 + ar;
            out[i0]      = xres[row][w * 32 + ar]      + a0[i];
            out[i0 + 16] = xres[row][w * 32 + 16 + ar] + a1[i];
        }
    }
}

extern "C" void kernel_launch(void* const* d_in, const int* in_sizes, int n_in,
                              void* d_out, int out_size, void* d_ws, size_t ws_size,
                              hipStream_t stream)
{
    const float* x   = (const float*)d_in[0];
    const float* n1  = (const float*)d_in[1];
    const float* anw = (const float*)d_in[2];
    const float* n2  = (const float*)d_in[3];
    const float* wq  = (const float*)d_in[4];
    const float* wk  = (const float*)d_in[5];
    const float* wv  = (const float*)d_in[6];
    const float* wo  = (const float*)d_in[7];
    const float* gw  = (const float*)d_in[8];
    const float* uw  = (const float*)d_in[9];
    const float* dw  = (const float*)d_in[10];
    float* out = (float*)d_out;

    float* ws = (float*)d_ws;
    short* qbf = (short*)ws;                   // [head][4096][32] bf16
    short* kbf = (short*)(ws + 262144);        // [head][4096][32]
    short* vbf = (short*)(ws + 524288);        // [head][4096][32]
    short* obf = (short*)(ws + 786432);        // [vox][128]
    short* wsw = (short*)(ws + 1048576);       // 262144 shorts

    k_prep<<<64,  512, 0, stream>>>(wq, wk, wv, wo, gw, uw, dw, wsw);
    k_qkv <<<256, 256, 0, stream>>>(x, n1, wsw, qbf, kbf, vbf);
    dim3 ga(128, 4);
    k_attn<<<ga,  256, 0, stream>>>(qbf, kbf, vbf, obf);
    k_post<<<256, 256, 0, stream>>>(obf, wsw, anw, x, n2, out);
}

// Round 17
// 36.744 us; speedup vs baseline: 5.1144x; 1.0205x over previous
//
#include <hip/hip_runtime.h>
#include <hip/hip_bf16.h>

#define NVOX 4096
#define C    128
#define HID  512
#define EPSF 1e-6f

typedef __attribute__((ext_vector_type(8))) short bf16x8;
typedef __attribute__((ext_vector_type(4))) float f32x4;

__device__ __forceinline__ short f2bs(float f) {
    __hip_bfloat16 h = __float2bfloat16(f);
    short s; __builtin_memcpy(&s, &h, 2); return s;
}
__device__ __forceinline__ float bs2f(unsigned short u) {
    return __uint_as_float(((unsigned)u) << 16);
}

// A-frag from swizzled LDS tile hs[16][128] (bf16 shorts, col ^ ((row&7)<<3))
__device__ __forceinline__ bf16x8 lda(const short* hs, int lane, int ks) {
    int r = lane & 15, g = lane >> 4;
    int col = (ks * 32 + g * 8) ^ ((r & 7) << 3);
    return *(const bf16x8*)(hs + r * 128 + col);
}

__device__ __forceinline__ float wave_rsum(float s) {
    s += __shfl_xor(s, 32); s += __shfl_xor(s, 16); s += __shfl_xor(s, 8);
    s += __shfl_xor(s, 4);  s += __shfl_xor(s, 2);  s += __shfl_xor(s, 1);
    return s;
}

// ---------- weight prep (wq/wk/wv only; rest folded into k_qkv) ----------
__global__ __launch_bounds__(512) void k_prep(
    const float* __restrict__ wq, const float* __restrict__ wk,
    const float* __restrict__ wv, short* __restrict__ wsw)
{
    int id = blockIdx.x * 512 + threadIdx.x;   // [0, 6144)
    int m = id >> 11, loc = id & 2047;
    const float* src = (m == 0) ? wq : (m == 1) ? wk : wv;
    int base = m << 14;
    int ct = loc >> 8, ks = (loc >> 6) & 3, lane = loc & 63;
    int k0 = ks * 32 + (lane >> 4) * 8;
    int c  = ct * 16 + (lane & 15);
    bf16x8 v;
    #pragma unroll
    for (int j = 0; j < 8; j++) v[j] = f2bs(src[(size_t)(k0 + j) * 128 + c]);
    *(bf16x8*)(wsw + base + (((ct * 4 + ks) * 64 + lane) << 3)) = v;
}

// ---------- K1: rmsnorm(x)*n1 -> q,k,v (bf16 head-major) + folded prep of wo/gw/uw/dw ----------
__global__ __launch_bounds__(256) void k_qkv(
    const float* __restrict__ x, const float* __restrict__ n1,
    const float* __restrict__ wo, const float* __restrict__ gw,
    const float* __restrict__ uw, const float* __restrict__ dw,
    short* __restrict__ wsw,
    short* __restrict__ qbf, short* __restrict__ kbf, short* __restrict__ vbf)
{
    __shared__ short hs[2048];
    const int r0 = blockIdx.x * 16, t = threadIdx.x;
    const int w = t >> 6, lane = t & 63;

    // folded prep: convert wo/gw/uw/dw slice (consumed only by k_post, 2 launches later)
    if (t < 104) {
        int gid = 6144 + blockIdx.x * 104 + t;    // [6144, 32768)
        const float* src; int base, ct, ks2, ln2, N, KS;
        if (gid < 8192)       { int loc = gid & 2047;  src = wo; base = 3 << 14; N = 128; KS = 4;
                                ct = loc >> 8; ks2 = (loc >> 6) & 3; ln2 = loc & 63; }
        else if (gid < 16384) { int loc = gid - 8192;  src = gw; base = 65536;  N = 512; KS = 4;
                                ct = loc >> 8; ks2 = (loc >> 6) & 3; ln2 = loc & 63; }
        else if (gid < 24576) { int loc = gid - 16384; src = uw; base = 131072; N = 512; KS = 4;
                                ct = loc >> 8; ks2 = (loc >> 6) & 3; ln2 = loc & 63; }
        else                  { int loc = gid - 24576; src = dw; base = 196608; N = 128; KS = 16;
                                ct = loc >> 10; ks2 = (loc >> 6) & 15; ln2 = loc & 63; }
        int k0 = ks2 * 32 + (ln2 >> 4) * 8;
        int c  = ct * 16 + (ln2 & 15);
        bf16x8 v;
        #pragma unroll
        for (int j = 0; j < 8; j++) v[j] = f2bs(src[(size_t)(k0 + j) * N + c]);
        *(bf16x8*)(wsw + base + (((ct * KS + ks2) * 64 + ln2) << 3)) = v;
    }

    #pragma unroll
    for (int i = 0; i < 4; i++) {
        int r = w * 4 + i;
        const float* xp = x + (size_t)(r0 + r) * 128;
        float v0 = xp[lane], v1 = xp[lane + 64];
        float s = wave_rsum(fmaf(v0, v0, v1 * v1));
        float sc = rsqrtf(s * (1.0f / 128.0f) + EPSF);
        int p3 = (r & 7) << 3;
        hs[r * 128 + (lane ^ p3)]        = f2bs(v0 * sc * n1[lane]);
        hs[r * 128 + ((lane + 64) ^ p3)] = f2bs(v1 * sc * n1[lane + 64]);
    }
    __syncthreads();

    bf16x8 af[4];
    #pragma unroll
    for (int ks = 0; ks < 4; ks++) af[ks] = lda(hs, lane, ks);

    const int rb = (lane >> 4) * 4, cl = lane & 15;
    #pragma unroll
    for (int m = 0; m < 3; m++) {
        const short* wb = wsw + (m << 14);
        f32x4 a0 = {0.f,0.f,0.f,0.f}, a1 = {0.f,0.f,0.f,0.f};
        #pragma unroll
        for (int ks = 0; ks < 4; ks++) {
            bf16x8 b0 = *(const bf16x8*)(wb + ((((w * 2) * 4 + ks) * 64 + lane) << 3));
            bf16x8 b1 = *(const bf16x8*)(wb + ((((w * 2 + 1) * 4 + ks) * 64 + lane) << 3));
            a0 = __builtin_amdgcn_mfma_f32_16x16x32_bf16(af[ks], b0, a0, 0, 0, 0);
            a1 = __builtin_amdgcn_mfma_f32_16x16x32_bf16(af[ks], b1, a1, 0, 0, 0);
        }
        short* outp = (m == 0) ? qbf : (m == 1) ? kbf : vbf;
        short* hp = outp + (size_t)w * NVOX * 32;    // wave w == head w
        #pragma unroll
        for (int i = 0; i < 4; i++) {
            hp[(size_t)(r0 + rb + i) * 32 + cl]      = f2bs(a0[i]);
            hp[(size_t)(r0 + rb + i) * 32 + 16 + cl] = f2bs(a1[i]);
        }
    }
}

// ---------- K2: MFMA brick attention (head-major in AND out; S transposed [q][key]) ----------
// block = (brick 4x4x2, head); halo 8x8x6 = 384 rows. 256 thr = 4 waves.
// LDS overlays: [K 30720 | S2 25088 | ... | Q 2560 | inv 128] -> [PA 24576 | VB 24576 | ...]
__global__ __launch_bounds__(256) void k_attn(
    const short* __restrict__ qbf, const short* __restrict__ kbf,
    const short* __restrict__ vbf, short* __restrict__ obf)
{
    __shared__ __align__(16) char smem[64128];
    short* K_lds = (short*)smem;             // [384][40] natural rows (phase 2)
    short* PA    = (short*)smem;             // P in A-frag order (phases 3,5)
    short* S2    = (short*)(smem + 30720);   // [32 q][392] bf16 scores (phases 2,3)
    short* VB    = (short*)(smem + 30720);   // V in B-frag order (phases 4,5)
    short* Q_lds = (short*)(smem + 61440);   // [32][40]
    float* inv   = (float*)(smem + 64000);   // [32]

    const int b = blockIdx.x, head = blockIdx.y, t = threadIdx.x;
    const int ow = (b & 3) * 4, oh = ((b >> 2) & 3) * 4, od = (b >> 4) * 2;
    const int w = t >> 6, lane = t & 63;
    const int g = lane >> 4, r = lane & 15;
    const short* kh = kbf + (size_t)head * NVOX * 32;
    const short* vh = vbf + (size_t)head * NVOX * 32;
    const short* qh = qbf + (size_t)head * NVOX * 32;
    short* oh_ = obf + (size_t)head * NVOX * 32;

    // ---- phase 1: stage K + Q; prefetch V rows into registers ----
    uint4 v0[4] = {}, v1[4] = {};
    {
        int row = t;
        int lw = row & 7, lh = (row >> 3) & 7, ld = row >> 6;
        int gd = od - 2 + ld, gh = oh - 2 + lh, gw_ = ow - 2 + lw;
        int sv = (((unsigned)gd < 16u) && ((unsigned)gh < 16u) && ((unsigned)gw_ < 16u));
        size_t off = (size_t)((((gd << 4) | gh) << 4) | gw_) * 32;
        uint4 kc[4];
        #pragma unroll
        for (int c2 = 0; c2 < 4; c2++) {
            kc[c2] = sv ? *(const uint4*)(kh + off + c2 * 8) : (uint4){0,0,0,0};
            v0[c2] = sv ? *(const uint4*)(vh + off + c2 * 8) : (uint4){0,0,0,0};
        }
        #pragma unroll
        for (int c2 = 0; c2 < 4; c2++) *(uint4*)&K_lds[row * 40 + c2 * 8] = kc[c2];

        if (t >= 128) {
            int row1 = t + 128;   // 256..383
            int lw1 = row1 & 7, lh1 = (row1 >> 3) & 7, ld1 = row1 >> 6;
            int gd1 = od - 2 + ld1, gh1 = oh - 2 + lh1, gw1 = ow - 2 + lw1;
            int sv1 = (((unsigned)gd1 < 16u) && ((unsigned)gh1 < 16u) && ((unsigned)gw1 < 16u));
            size_t off1 = (size_t)((((gd1 << 4) | gh1) << 4) | gw1) * 32;
            uint4 kd[4];
            #pragma unroll
            for (int c2 = 0; c2 < 4; c2++) {
                kd[c2] = sv1 ? *(const uint4*)(kh + off1 + c2 * 8) : (uint4){0,0,0,0};
                v1[c2] = sv1 ? *(const uint4*)(vh + off1 + c2 * 8) : (uint4){0,0,0,0};
            }
            #pragma unroll
            for (int c2 = 0; c2 < 4; c2++) *(uint4*)&K_lds[row1 * 40 + c2 * 8] = kd[c2];
        } else {
            int q = t >> 2, c2q = t & 3;
            int gq = ((od + (q >> 4)) << 8) | ((oh + ((q >> 2) & 3)) << 4) | (ow + (q & 3));
            *(uint4*)&Q_lds[q * 40 + c2q * 8] = *(const uint4*)(qh + (size_t)gq * 32 + c2q * 8);
        }
    }
    __syncthreads();

    // ---- phase 2: S[q][key] = (K · Q^T)^T — packed b64 stores of 4 consecutive keys ----
    {
        bf16x8 bq0 = *(const bf16x8*)(Q_lds + r * 40 + g * 8);          // queries 0..15
        bf16x8 bq1 = *(const bf16x8*)(Q_lds + (16 + r) * 40 + g * 8);   // queries 16..31
        #pragma unroll
        for (int jj = 0; jj < 6; jj++) {
            int mt = w + jj * 4;                 // key tile
            bf16x8 ak = *(const bf16x8*)(K_lds + (mt * 16 + r) * 40 + g * 8);
            f32x4 a0 = {0.f,0.f,0.f,0.f}, a1 = {0.f,0.f,0.f,0.f};
            a0 = __builtin_amdgcn_mfma_f32_16x16x32_bf16(ak, bq0, a0, 0, 0, 0);
            a1 = __builtin_amdgcn_mfma_f32_16x16x32_bf16(ak, bq1, a1, 0, 0, 0);
            int key0 = mt * 16 + g * 4;
            short s4[4];
            #pragma unroll
            for (int i = 0; i < 4; i++) s4[i] = f2bs(a0[i]);
            unsigned long long pk0; __builtin_memcpy(&pk0, s4, 8);
            *(unsigned long long*)&S2[r * 392 + key0] = pk0;
            #pragma unroll
            for (int i = 0; i < 4; i++) s4[i] = f2bs(a1[i]);
            unsigned long long pk1; __builtin_memcpy(&pk1, s4, 8);
            *(unsigned long long*)&S2[(16 + r) * 392 + key0] = pk1;
        }
    }
    __syncthreads();

    // ---- phase 3: masked softmax; thread (q, kl) owns contiguous keys [48*kl, 48*kl+48) ----
    {
        const int q = t >> 3, kl = t & 7;
        const int qw_ = q & 3, qh_ = (q >> 2) & 3, qd_ = q >> 4;
        const float isq = 0.17677669529663687f;   // 1/sqrt(32)
        uint4 sraw[6];
        #pragma unroll
        for (int jj = 0; jj < 6; jj++)
            sraw[jj] = *(const uint4*)&S2[q * 392 + kl * 48 + jj * 8];
        unsigned long long okb = 0;
        float mx = -1e30f;
        #pragma unroll
        for (int jj = 0; jj < 6; jj++) {
            const unsigned short* u = (const unsigned short*)&sraw[jj];
            #pragma unroll
            for (int e = 0; e < 8; e++) {
                int k = kl * 48 + jj * 8 + e;
                int lw = k & 7, lh = (k >> 3) & 7, ld = k >> 6;
                int ok = ((unsigned)(ld - qd_) <= 4u) & ((unsigned)(lh - qh_) <= 4u)
                       & ((unsigned)(lw - qw_) <= 4u)
                       & ((unsigned)(od - 2 + ld) < 16u) & ((unsigned)(oh - 2 + lh) < 16u)
                       & ((unsigned)(ow - 2 + lw) < 16u);
                float s = bs2f(u[e]) * isq;
                mx = ok ? fmaxf(mx, s) : mx;
                okb |= ((unsigned long long)ok) << (jj * 8 + e);
            }
        }
        mx = fmaxf(mx, __shfl_xor(mx, 1));
        mx = fmaxf(mx, __shfl_xor(mx, 2));
        mx = fmaxf(mx, __shfl_xor(mx, 4));
        float ssum = 0.f;
        #pragma unroll
        for (int jj = 0; jj < 6; jj++) {
            const unsigned short* u = (const unsigned short*)&sraw[jj];
            #pragma unroll
            for (int e = 0; e < 8; e++) {
                int k = kl * 48 + jj * 8 + e;
                float s = bs2f(u[e]) * isq;
                float p = ((okb >> (jj * 8 + e)) & 1) ? __expf(s - mx) : 0.f;
                ssum += p;
                PA[((q >> 4) * 12 + (k >> 5)) * 512 + ((k >> 3) & 3) * 128 + (q & 15) * 8 + (k & 7)] = f2bs(p);
            }
        }
        ssum += __shfl_xor(ssum, 1);
        ssum += __shfl_xor(ssum, 2);
        ssum += __shfl_xor(ssum, 4);
        if (kl == 0) inv[q] = 1.0f / ssum;
    }
    __syncthreads();

    // ---- phase 4: write V rows (from registers) into B-frag order ----
    {
        int row = t;
        int ks = row >> 5, g3 = (row >> 3) & 3, j3 = row & 7;
        const unsigned short* u = (const unsigned short*)v0;
        #pragma unroll
        for (int c = 0; c < 32; c++)
            VB[((c >> 4) * 12 + ks) * 512 + g3 * 128 + (c & 15) * 8 + j3] = (short)u[c];
        if (t >= 128) {
            int row1 = t + 128;
            int ks1 = row1 >> 5, g31 = (row1 >> 3) & 3, j31 = row1 & 7;
            const unsigned short* u1 = (const unsigned short*)v1;
            #pragma unroll
            for (int c = 0; c < 32; c++)
                VB[((c >> 4) * 12 + ks1) * 512 + g31 * 128 + (c & 15) * 8 + j31] = (short)u1[c];
        }
    }
    __syncthreads();

    // ---- phase 5: O[q][c] = P · V  (head-major output) ----
    {
        const int mt2 = w >> 1, ct = w & 1;
        f32x4 acc = {0.f,0.f,0.f,0.f};
        #pragma unroll
        for (int ks = 0; ks < 12; ks++) {
            bf16x8 pa = *(const bf16x8*)(PA + (((mt2 * 12 + ks) * 64 + lane) << 3));
            bf16x8 vb = *(const bf16x8*)(VB + (((ct * 12 + ks) * 64 + lane) << 3));
            acc = __builtin_amdgcn_mfma_f32_16x16x32_bf16(pa, vb, acc, 0, 0, 0);
        }
        #pragma unroll
        for (int i = 0; i < 4; i++) {
            int q = mt2 * 16 + g * 4 + i;
            int c = ct * 16 + r;
            int gvox = ((od + (q >> 4)) << 8) | ((oh + ((q >> 2) & 3)) << 4) | (ow + (q & 3));
            oh_[(size_t)gvox * 32 + c] = f2bs(acc[i] * inv[q]);
        }
    }
}

// ---------- K3: fused post-chain (obf head-major reads) ----------
__global__ __launch_bounds__(256) void k_post(
    const short* __restrict__ obf, const short* __restrict__ wsw,
    const float* __restrict__ anw, const float* __restrict__ x,
    const float* __restrict__ n2w, float* __restrict__ out)
{
    __shared__ float ybuf[16][132];
    __shared__ float xres[16][128];
    __shared__ short hs[2048];
    __shared__ short gu[16 * 512];

    const int r0 = blockIdx.x * 16, t = threadIdx.x;
    const int w = t >> 6, lane = t & 63;
    const int ar = lane & 15, ag_ = lane >> 4;

    // phase 1: y = o @ wo   (obf head-major: head = ks)
    {
        const short* wb = wsw + (3 << 14);
        f32x4 a0 = {0.f,0.f,0.f,0.f}, a1 = {0.f,0.f,0.f,0.f};
        #pragma unroll
        for (int ks = 0; ks < 4; ks++) {
            bf16x8 a = *(const bf16x8*)(obf + (size_t)ks * NVOX * 32 + (size_t)(r0 + ar) * 32 + ag_ * 8);
            bf16x8 b0 = *(const bf16x8*)(wb + ((((w * 2) * 4 + ks) * 64 + lane) << 3));
            bf16x8 b1 = *(const bf16x8*)(wb + ((((w * 2 + 1) * 4 + ks) * 64 + lane) << 3));
            a0 = __builtin_amdgcn_mfma_f32_16x16x32_bf16(a, b0, a0, 0, 0, 0);
            a1 = __builtin_amdgcn_mfma_f32_16x16x32_bf16(a, b1, a1, 0, 0, 0);
        }
        #pragma unroll
        for (int i = 0; i < 4; i++) {
            ybuf[ag_ * 4 + i][w * 32 + ar]      = a0[i];
            ybuf[ag_ * 4 + i][w * 32 + 16 + ar] = a1[i];
        }
    }
    __syncthreads();

    // phase 2+3 fused, per-wave: xres = x + rmsnorm(y)*anw; hs = rmsnorm(xres)*n2w
    #pragma unroll
    for (int i = 0; i < 4; i++) {
        int r = w * 4 + i;
        float y0 = ybuf[r][lane], y1 = ybuf[r][lane + 64];
        float s = wave_rsum(fmaf(y0, y0, y1 * y1));
        float sc = rsqrtf(s * (1.0f / 128.0f) + EPSF);
        const float* xp = x + (size_t)(r0 + r) * 128;
        float xr0 = xp[lane]      + y0 * sc * anw[lane];
        float xr1 = xp[lane + 64] + y1 * sc * anw[lane + 64];
        xres[r][lane] = xr0; xres[r][lane + 64] = xr1;
        float s2 = wave_rsum(fmaf(xr0, xr0, xr1 * xr1));
        float sc2 = rsqrtf(s2 * (1.0f / 128.0f) + EPSF);
        int p3 = (r & 7) << 3;
        hs[r * 128 + (lane ^ p3)]        = f2bs(xr0 * sc2 * n2w[lane]);
        hs[r * 128 + ((lane + 64) ^ p3)] = f2bs(xr1 * sc2 * n2w[lane + 64]);
    }
    __syncthreads();

    // phase 4: gu = silu(h2@gw)*(h2@uw)  (4 waves x 8 col-tiles)
    {
        const short* gwb = wsw + 65536;
        const short* uwb = wsw + 131072;
        bf16x8 af[4];
        #pragma unroll
        for (int ks = 0; ks < 4; ks++) af[ks] = lda(hs, lane, ks);
        f32x4 ag[8], au[8];
        #pragma unroll
        for (int i = 0; i < 8; i++) { ag[i] = (f32x4){0.f,0.f,0.f,0.f}; au[i] = (f32x4){0.f,0.f,0.f,0.f}; }
        #pragma unroll
        for (int ks = 0; ks < 4; ks++) {
            #pragma unroll
            for (int i = 0; i < 8; i++) {
                int ct = w * 8 + i;
                bf16x8 bg = *(const bf16x8*)(gwb + (((ct * 4 + ks) * 64 + lane) << 3));
                bf16x8 bu = *(const bf16x8*)(uwb + (((ct * 4 + ks) * 64 + lane) << 3));
                ag[i] = __builtin_amdgcn_mfma_f32_16x16x32_bf16(af[ks], bg, ag[i], 0, 0, 0);
                au[i] = __builtin_amdgcn_mfma_f32_16x16x32_bf16(af[ks], bu, au[i], 0, 0, 0);
            }
        }
        #pragma unroll
        for (int i = 0; i < 8; i++) {
            int col = (w * 8 + i) * 16 + ar;
            #pragma unroll
            for (int j = 0; j < 4; j++) {
                int row = ag_ * 4 + j;
                float g = ag[i][j], uu = au[i][j];
                float sg = g / (1.0f + __expf(-g));
                gu[row * 512 + (col ^ ((row & 7) << 3))] = f2bs(sg * uu);
            }
        }
    }
    __syncthreads();

    // phase 5: out = xres + gu @ dw (K=512)
    {
        const short* db = wsw + 196608;
        f32x4 a0 = {0.f,0.f,0.f,0.f}, a1 = {0.f,0.f,0.f,0.f};
        #pragma unroll
        for (int ks = 0; ks < 16; ks++) {
            int col = (ks * 32 + ag_ * 8) ^ ((ar & 7) << 3);
            bf16x8 a = *(const bf16x8*)(gu + ar * 512 + col);
            bf16x8 b0 = *(const bf16x8*)(db + ((((w * 2) * 16 + ks) * 64 + lane) << 3));
            bf16x8 b1 = *(const bf16x8*)(db + ((((w * 2 + 1) * 16 + ks) * 64 + lane) << 3));
            a0 = __builtin_amdgcn_mfma_f32_16x16x32_bf16(a, b0, a0, 0, 0, 0);
            a1 = __builtin_amdgcn_mfma_f32_16x16x32_bf16(a, b1, a1, 0, 0, 0);
        }
        #pragma unroll
        for (int i = 0; i < 4; i++) {
            int row = ag_ * 4 + i;
            size_t i0 = (size_t)(r0 + row) * 128 + w * 32 + ar;
            out[i0]      = xres[row][w * 32 + ar]      + a0[i];
            out[i0 + 16] = xres[row][w * 32 + 16 + ar] + a1[i];
        }
    }
}

extern "C" void kernel_launch(void* const* d_in, const int* in_sizes, int n_in,
                              void* d_out, int out_size, void* d_ws, size_t ws_size,
                              hipStream_t stream)
{
    const float* x   = (const float*)d_in[0];
    const float* n1  = (const float*)d_in[1];
    const float* anw = (const float*)d_in[2];
    const float* n2  = (const float*)d_in[3];
    const float* wq  = (const float*)d_in[4];
    const float* wk  = (const float*)d_in[5];
    const float* wv  = (const float*)d_in[6];
    const float* wo  = (const float*)d_in[7];
    const float* gw  = (const float*)d_in[8];
    const float* uw  = (const float*)d_in[9];
    const float* dw  = (const float*)d_in[10];
    float* out = (float*)d_out;

    float* ws = (float*)d_ws;
    short* qbf = (short*)ws;                   // [head][4096][32] bf16
    short* kbf = (short*)(ws + 262144);        // [head][4096][32]
    short* vbf = (short*)(ws + 524288);        // [head][4096][32]
    short* obf = (short*)(ws + 786432);        // [head][4096][32]
    short* wsw = (short*)(ws + 1048576);       // 262144 shorts

    k_prep<<<12,  512, 0, stream>>>(wq, wk, wv, wsw);
    k_qkv <<<256, 256, 0, stream>>>(x, n1, wo, gw, uw, dw, wsw, qbf, kbf, vbf);
    dim3 ga(128, 4);
    k_attn<<<ga,  256, 0, stream>>>(qbf, kbf, vbf, obf);
    k_post<<<256, 256, 0, stream>>>(obf, wsw, anw, x, n2, out);
}

// Round 18
// 33.499 us; speedup vs baseline: 5.6098x; 1.0969x over previous
//
#include <hip/hip_runtime.h>
#include <hip/hip_bf16.h>

#define NVOX 4096
#define C    128
#define HID  512
#define EPSF 1e-6f

typedef __attribute__((ext_vector_type(8))) short bf16x8;
typedef __attribute__((ext_vector_type(4))) float f32x4;

__device__ __forceinline__ short f2bs(float f) {
    __hip_bfloat16 h = __float2bfloat16(f);
    short s; __builtin_memcpy(&s, &h, 2); return s;
}
__device__ __forceinline__ float bs2f(unsigned short u) {
    return __uint_as_float(((unsigned)u) << 16);
}

// A-frag from swizzled LDS tile hs[16][128] (bf16 shorts, col ^ ((row&7)<<3))
__device__ __forceinline__ bf16x8 lda(const short* hs, int lane, int ks) {
    int r = lane & 15, g = lane >> 4;
    int col = (ks * 32 + g * 8) ^ ((r & 7) << 3);
    return *(const bf16x8*)(hs + r * 128 + col);
}

__device__ __forceinline__ float wave_rsum(float s) {
    s += __shfl_xor(s, 32); s += __shfl_xor(s, 16); s += __shfl_xor(s, 8);
    s += __shfl_xor(s, 4);  s += __shfl_xor(s, 2);  s += __shfl_xor(s, 1);
    return s;
}

// ---------- K1 (512 thr, 8 waves): rmsnorm -> q,k,v head-major; qkv weights read
// directly from fp32 (no prep); folded prep of wo/gw/uw/dw for k_post ----------
__global__ __launch_bounds__(512) void k_qkv(
    const float* __restrict__ x, const float* __restrict__ n1,
    const float* __restrict__ wq, const float* __restrict__ wk,
    const float* __restrict__ wv,
    const float* __restrict__ wo, const float* __restrict__ gw,
    const float* __restrict__ uw, const float* __restrict__ dw,
    short* __restrict__ wsw,
    short* __restrict__ qbf, short* __restrict__ kbf, short* __restrict__ vbf)
{
    __shared__ short hs[2048];
    const int r0 = blockIdx.x * 16, t = threadIdx.x;
    const int w = t >> 6, lane = t & 63;
    const int g = lane >> 4, r = lane & 15;

    // folded prep: convert wo/gw/uw/dw (consumed only by k_post, 2 launches later)
    if (t < 104) {
        int gid = 6144 + blockIdx.x * 104 + t;    // [6144, 32768)
        const float* src; int base, ct, ks2, ln2, N, KS;
        if (gid < 8192)       { int loc = gid & 2047;  src = wo; base = 3 << 14; N = 128; KS = 4;
                                ct = loc >> 8; ks2 = (loc >> 6) & 3; ln2 = loc & 63; }
        else if (gid < 16384) { int loc = gid - 8192;  src = gw; base = 65536;  N = 512; KS = 4;
                                ct = loc >> 8; ks2 = (loc >> 6) & 3; ln2 = loc & 63; }
        else if (gid < 24576) { int loc = gid - 16384; src = uw; base = 131072; N = 512; KS = 4;
                                ct = loc >> 8; ks2 = (loc >> 6) & 3; ln2 = loc & 63; }
        else                  { int loc = gid - 24576; src = dw; base = 196608; N = 128; KS = 16;
                                ct = loc >> 10; ks2 = (loc >> 6) & 15; ln2 = loc & 63; }
        int k0 = ks2 * 32 + (ln2 >> 4) * 8;
        int c  = ct * 16 + (ln2 & 15);
        bf16x8 v;
        #pragma unroll
        for (int j = 0; j < 8; j++) v[j] = f2bs(src[(size_t)(k0 + j) * N + c]);
        *(bf16x8*)(wsw + base + (((ct * KS + ks2) * 64 + ln2) << 3)) = v;
    }

    // per-wave rmsnorm: wave w owns rows 2w, 2w+1
    #pragma unroll
    for (int i = 0; i < 2; i++) {
        int rr = w * 2 + i;
        const float* xp = x + (size_t)(r0 + rr) * 128;
        float v0 = xp[lane], v1 = xp[lane + 64];
        float s = wave_rsum(fmaf(v0, v0, v1 * v1));
        float sc = rsqrtf(s * (1.0f / 128.0f) + EPSF);
        int p3 = (rr & 7) << 3;
        hs[rr * 128 + (lane ^ p3)]        = f2bs(v0 * sc * n1[lane]);
        hs[rr * 128 + ((lane + 64) ^ p3)] = f2bs(v1 * sc * n1[lane + 64]);
    }
    __syncthreads();

    bf16x8 af[4];
    #pragma unroll
    for (int ks = 0; ks < 4; ks++) af[ks] = lda(hs, lane, ks);

    const int rb = g * 4;
    // 24 col-tiles over [q|k|v]; wave w does tiles 3w..3w+2
    #pragma unroll
    for (int i = 0; i < 3; i++) {
        int gt = w * 3 + i;
        int m = gt >> 3, ct = gt & 7;
        const float* srcw = (m == 0) ? wq : (m == 1) ? wk : wv;
        const float* wp = srcw + ct * 16 + r;
        f32x4 a0 = {0.f,0.f,0.f,0.f};
        #pragma unroll
        for (int ks = 0; ks < 4; ks++) {
            const float* wpk = wp + (size_t)(ks * 32 + g * 8) * 128;
            bf16x8 b0;
            #pragma unroll
            for (int j = 0; j < 8; j++) b0[j] = f2bs(wpk[(size_t)j * 128]);
            a0 = __builtin_amdgcn_mfma_f32_16x16x32_bf16(af[ks], b0, a0, 0, 0, 0);
        }
        short* outp = (m == 0) ? qbf : (m == 1) ? kbf : vbf;
        short* hp = outp + (size_t)(ct >> 1) * NVOX * 32;
        int col = (ct & 1) * 16 + r;
        #pragma unroll
        for (int j = 0; j < 4; j++)
            hp[(size_t)(r0 + rb + j) * 32 + col] = f2bs(a0[j]);
    }
}

// ---------- K2: MFMA brick attention (unchanged from round 17) ----------
__global__ __launch_bounds__(256) void k_attn(
    const short* __restrict__ qbf, const short* __restrict__ kbf,
    const short* __restrict__ vbf, short* __restrict__ obf)
{
    __shared__ __align__(16) char smem[64128];
    short* K_lds = (short*)smem;             // [384][40] natural rows (phase 2)
    short* PA    = (short*)smem;             // P in A-frag order (phases 3,5)
    short* S2    = (short*)(smem + 30720);   // [32 q][392] bf16 scores (phases 2,3)
    short* VB    = (short*)(smem + 30720);   // V in B-frag order (phases 4,5)
    short* Q_lds = (short*)(smem + 61440);   // [32][40]
    float* inv   = (float*)(smem + 64000);   // [32]

    const int b = blockIdx.x, head = blockIdx.y, t = threadIdx.x;
    const int ow = (b & 3) * 4, oh = ((b >> 2) & 3) * 4, od = (b >> 4) * 2;
    const int w = t >> 6, lane = t & 63;
    const int g = lane >> 4, r = lane & 15;
    const short* kh = kbf + (size_t)head * NVOX * 32;
    const short* vh = vbf + (size_t)head * NVOX * 32;
    const short* qh = qbf + (size_t)head * NVOX * 32;
    short* oh_ = obf + (size_t)head * NVOX * 32;

    // ---- phase 1: stage K + Q; prefetch V rows into registers ----
    uint4 v0[4] = {}, v1[4] = {};
    {
        int row = t;
        int lw = row & 7, lh = (row >> 3) & 7, ld = row >> 6;
        int gd = od - 2 + ld, gh = oh - 2 + lh, gw_ = ow - 2 + lw;
        int sv = (((unsigned)gd < 16u) && ((unsigned)gh < 16u) && ((unsigned)gw_ < 16u));
        size_t off = (size_t)((((gd << 4) | gh) << 4) | gw_) * 32;
        uint4 kc[4];
        #pragma unroll
        for (int c2 = 0; c2 < 4; c2++) {
            kc[c2] = sv ? *(const uint4*)(kh + off + c2 * 8) : (uint4){0,0,0,0};
            v0[c2] = sv ? *(const uint4*)(vh + off + c2 * 8) : (uint4){0,0,0,0};
        }
        #pragma unroll
        for (int c2 = 0; c2 < 4; c2++) *(uint4*)&K_lds[row * 40 + c2 * 8] = kc[c2];

        if (t >= 128) {
            int row1 = t + 128;   // 256..383
            int lw1 = row1 & 7, lh1 = (row1 >> 3) & 7, ld1 = row1 >> 6;
            int gd1 = od - 2 + ld1, gh1 = oh - 2 + lh1, gw1 = ow - 2 + lw1;
            int sv1 = (((unsigned)gd1 < 16u) && ((unsigned)gh1 < 16u) && ((unsigned)gw1 < 16u));
            size_t off1 = (size_t)((((gd1 << 4) | gh1) << 4) | gw1) * 32;
            uint4 kd[4];
            #pragma unroll
            for (int c2 = 0; c2 < 4; c2++) {
                kd[c2] = sv1 ? *(const uint4*)(kh + off1 + c2 * 8) : (uint4){0,0,0,0};
                v1[c2] = sv1 ? *(const uint4*)(vh + off1 + c2 * 8) : (uint4){0,0,0,0};
            }
            #pragma unroll
            for (int c2 = 0; c2 < 4; c2++) *(uint4*)&K_lds[row1 * 40 + c2 * 8] = kd[c2];
        } else {
            int q = t >> 2, c2q = t & 3;
            int gq = ((od + (q >> 4)) << 8) | ((oh + ((q >> 2) & 3)) << 4) | (ow + (q & 3));
            *(uint4*)&Q_lds[q * 40 + c2q * 8] = *(const uint4*)(qh + (size_t)gq * 32 + c2q * 8);
        }
    }
    __syncthreads();

    // ---- phase 2: S[q][key] = (K · Q^T)^T — packed b64 stores ----
    {
        bf16x8 bq0 = *(const bf16x8*)(Q_lds + r * 40 + g * 8);
        bf16x8 bq1 = *(const bf16x8*)(Q_lds + (16 + r) * 40 + g * 8);
        #pragma unroll
        for (int jj = 0; jj < 6; jj++) {
            int mt = w + jj * 4;
            bf16x8 ak = *(const bf16x8*)(K_lds + (mt * 16 + r) * 40 + g * 8);
            f32x4 a0 = {0.f,0.f,0.f,0.f}, a1 = {0.f,0.f,0.f,0.f};
            a0 = __builtin_amdgcn_mfma_f32_16x16x32_bf16(ak, bq0, a0, 0, 0, 0);
            a1 = __builtin_amdgcn_mfma_f32_16x16x32_bf16(ak, bq1, a1, 0, 0, 0);
            int key0 = mt * 16 + g * 4;
            short s4[4];
            #pragma unroll
            for (int i = 0; i < 4; i++) s4[i] = f2bs(a0[i]);
            unsigned long long pk0; __builtin_memcpy(&pk0, s4, 8);
            *(unsigned long long*)&S2[r * 392 + key0] = pk0;
            #pragma unroll
            for (int i = 0; i < 4; i++) s4[i] = f2bs(a1[i]);
            unsigned long long pk1; __builtin_memcpy(&pk1, s4, 8);
            *(unsigned long long*)&S2[(16 + r) * 392 + key0] = pk1;
        }
    }
    __syncthreads();

    // ---- phase 3: masked softmax; thread (q, kl) owns keys [48*kl, 48*kl+48) ----
    {
        const int q = t >> 3, kl = t & 7;
        const int qw_ = q & 3, qh_ = (q >> 2) & 3, qd_ = q >> 4;
        const float isq = 0.17677669529663687f;
        uint4 sraw[6];
        #pragma unroll
        for (int jj = 0; jj < 6; jj++)
            sraw[jj] = *(const uint4*)&S2[q * 392 + kl * 48 + jj * 8];
        unsigned long long okb = 0;
        float mx = -1e30f;
        #pragma unroll
        for (int jj = 0; jj < 6; jj++) {
            const unsigned short* u = (const unsigned short*)&sraw[jj];
            #pragma unroll
            for (int e = 0; e < 8; e++) {
                int k = kl * 48 + jj * 8 + e;
                int lw = k & 7, lh = (k >> 3) & 7, ld = k >> 6;
                int ok = ((unsigned)(ld - qd_) <= 4u) & ((unsigned)(lh - qh_) <= 4u)
                       & ((unsigned)(lw - qw_) <= 4u)
                       & ((unsigned)(od - 2 + ld) < 16u) & ((unsigned)(oh - 2 + lh) < 16u)
                       & ((unsigned)(ow - 2 + lw) < 16u);
                float s = bs2f(u[e]) * isq;
                mx = ok ? fmaxf(mx, s) : mx;
                okb |= ((unsigned long long)ok) << (jj * 8 + e);
            }
        }
        mx = fmaxf(mx, __shfl_xor(mx, 1));
        mx = fmaxf(mx, __shfl_xor(mx, 2));
        mx = fmaxf(mx, __shfl_xor(mx, 4));
        float ssum = 0.f;
        #pragma unroll
        for (int jj = 0; jj < 6; jj++) {
            const unsigned short* u = (const unsigned short*)&sraw[jj];
            #pragma unroll
            for (int e = 0; e < 8; e++) {
                int k = kl * 48 + jj * 8 + e;
                float s = bs2f(u[e]) * isq;
                float p = ((okb >> (jj * 8 + e)) & 1) ? __expf(s - mx) : 0.f;
                ssum += p;
                PA[((q >> 4) * 12 + (k >> 5)) * 512 + ((k >> 3) & 3) * 128 + (q & 15) * 8 + (k & 7)] = f2bs(p);
            }
        }
        ssum += __shfl_xor(ssum, 1);
        ssum += __shfl_xor(ssum, 2);
        ssum += __shfl_xor(ssum, 4);
        if (kl == 0) inv[q] = 1.0f / ssum;
    }
    __syncthreads();

    // ---- phase 4: write V rows (from registers) into B-frag order ----
    {
        int row = t;
        int ks = row >> 5, g3 = (row >> 3) & 3, j3 = row & 7;
        const unsigned short* u = (const unsigned short*)v0;
        #pragma unroll
        for (int c = 0; c < 32; c++)
            VB[((c >> 4) * 12 + ks) * 512 + g3 * 128 + (c & 15) * 8 + j3] = (short)u[c];
        if (t >= 128) {
            int row1 = t + 128;
            int ks1 = row1 >> 5, g31 = (row1 >> 3) & 3, j31 = row1 & 7;
            const unsigned short* u1 = (const unsigned short*)v1;
            #pragma unroll
            for (int c = 0; c < 32; c++)
                VB[((c >> 4) * 12 + ks1) * 512 + g31 * 128 + (c & 15) * 8 + j31] = (short)u1[c];
        }
    }
    __syncthreads();

    // ---- phase 5: O[q][c] = P · V  (head-major output) ----
    {
        const int mt2 = w >> 1, ct = w & 1;
        f32x4 acc = {0.f,0.f,0.f,0.f};
        #pragma unroll
        for (int ks = 0; ks < 12; ks++) {
            bf16x8 pa = *(const bf16x8*)(PA + (((mt2 * 12 + ks) * 64 + lane) << 3));
            bf16x8 vb = *(const bf16x8*)(VB + (((ct * 12 + ks) * 64 + lane) << 3));
            acc = __builtin_amdgcn_mfma_f32_16x16x32_bf16(pa, vb, acc, 0, 0, 0);
        }
        #pragma unroll
        for (int i = 0; i < 4; i++) {
            int q = mt2 * 16 + g * 4 + i;
            int c = ct * 16 + r;
            int gvox = ((od + (q >> 4)) << 8) | ((oh + ((q >> 2) & 3)) << 4) | (ow + (q & 3));
            oh_[(size_t)gvox * 32 + c] = f2bs(acc[i] * inv[q]);
        }
    }
}

// ---------- K3 (512 thr, 8 waves): fused post-chain ----------
__global__ __launch_bounds__(512) void k_post(
    const short* __restrict__ obf, const short* __restrict__ wsw,
    const float* __restrict__ anw, const float* __restrict__ x,
    const float* __restrict__ n2w, float* __restrict__ out)
{
    __shared__ float ybuf[16][132];
    __shared__ float xres[16][128];
    __shared__ short hs[2048];
    __shared__ short gu[16 * 512];

    const int r0 = blockIdx.x * 16, t = threadIdx.x;
    const int w = t >> 6, lane = t & 63;
    const int ar = lane & 15, ag_ = lane >> 4;

    // phase 1: y = o @ wo  (8 waves x one 16-col tile; obf head-major: head = ks)
    {
        const short* wb = wsw + (3 << 14);
        f32x4 a0 = {0.f,0.f,0.f,0.f};
        #pragma unroll
        for (int ks = 0; ks < 4; ks++) {
            bf16x8 a = *(const bf16x8*)(obf + (size_t)ks * NVOX * 32 + (size_t)(r0 + ar) * 32 + ag_ * 8);
            bf16x8 b0 = *(const bf16x8*)(wb + (((w * 4 + ks) * 64 + lane) << 3));
            a0 = __builtin_amdgcn_mfma_f32_16x16x32_bf16(a, b0, a0, 0, 0, 0);
        }
        #pragma unroll
        for (int i = 0; i < 4; i++)
            ybuf[ag_ * 4 + i][w * 16 + ar] = a0[i];
    }
    __syncthreads();

    // phase 2+3 fused, per-wave: wave w owns rows 2w, 2w+1
    #pragma unroll
    for (int i = 0; i < 2; i++) {
        int r = w * 2 + i;
        float y0 = ybuf[r][lane], y1 = ybuf[r][lane + 64];
        float s = wave_rsum(fmaf(y0, y0, y1 * y1));
        float sc = rsqrtf(s * (1.0f / 128.0f) + EPSF);
        const float* xp = x + (size_t)(r0 + r) * 128;
        float xr0 = xp[lane]      + y0 * sc * anw[lane];
        float xr1 = xp[lane + 64] + y1 * sc * anw[lane + 64];
        xres[r][lane] = xr0; xres[r][lane + 64] = xr1;
        float s2 = wave_rsum(fmaf(xr0, xr0, xr1 * xr1));
        float sc2 = rsqrtf(s2 * (1.0f / 128.0f) + EPSF);
        int p3 = (r & 7) << 3;
        hs[r * 128 + (lane ^ p3)]        = f2bs(xr0 * sc2 * n2w[lane]);
        hs[r * 128 + ((lane + 64) ^ p3)] = f2bs(xr1 * sc2 * n2w[lane + 64]);
    }
    __syncthreads();

    // phase 4: gu = silu(h2@gw)*(h2@uw)  (8 waves x 4 col-tiles)
    {
        const short* gwb = wsw + 65536;
        const short* uwb = wsw + 131072;
        bf16x8 af[4];
        #pragma unroll
        for (int ks = 0; ks < 4; ks++) af[ks] = lda(hs, lane, ks);
        f32x4 ag[4], au[4];
        #pragma unroll
        for (int i = 0; i < 4; i++) { ag[i] = (f32x4){0.f,0.f,0.f,0.f}; au[i] = (f32x4){0.f,0.f,0.f,0.f}; }
        #pragma unroll
        for (int ks = 0; ks < 4; ks++) {
            #pragma unroll
            for (int i = 0; i < 4; i++) {
                int ct = w * 4 + i;
                bf16x8 bg = *(const bf16x8*)(gwb + (((ct * 4 + ks) * 64 + lane) << 3));
                bf16x8 bu = *(const bf16x8*)(uwb + (((ct * 4 + ks) * 64 + lane) << 3));
                ag[i] = __builtin_amdgcn_mfma_f32_16x16x32_bf16(af[ks], bg, ag[i], 0, 0, 0);
                au[i] = __builtin_amdgcn_mfma_f32_16x16x32_bf16(af[ks], bu, au[i], 0, 0, 0);
            }
        }
        #pragma unroll
        for (int i = 0; i < 4; i++) {
            int col = (w * 4 + i) * 16 + ar;
            #pragma unroll
            for (int j = 0; j < 4; j++) {
                int row = ag_ * 4 + j;
                float g = ag[i][j], uu = au[i][j];
                float sg = g / (1.0f + __expf(-g));
                gu[row * 512 + (col ^ ((row & 7) << 3))] = f2bs(sg * uu);
            }
        }
    }
    __syncthreads();

    // phase 5: out = xres + gu @ dw  (8 waves x one 16-col tile, K=512)
    {
        const short* db = wsw + 196608;
        f32x4 a0 = {0.f,0.f,0.f,0.f};
        #pragma unroll
        for (int ks = 0; ks < 16; ks++) {
            int col = (ks * 32 + ag_ * 8) ^ ((ar & 7) << 3);
            bf16x8 a = *(const bf16x8*)(gu + ar * 512 + col);
            bf16x8 b0 = *(const bf16x8*)(db + (((w * 16 + ks) * 64 + lane) << 3));
            a0 = __builtin_amdgcn_mfma_f32_16x16x32_bf16(a, b0, a0, 0, 0, 0);
        }
        #pragma unroll
        for (int i = 0; i < 4; i++) {
            int row = ag_ * 4 + i;
            size_t i0 = (size_t)(r0 + row) * 128 + w * 16 + ar;
            out[i0] = xres[row][w * 16 + ar] + a0[i];
        }
    }
}

extern "C" void kernel_launch(void* const* d_in, const int* in_sizes, int n_in,
                              void* d_out, int out_size, void* d_ws, size_t ws_size,
                              hipStream_t stream)
{
    const float* x   = (const float*)d_in[0];
    const float* n1  = (const float*)d_in[1];
    const float* anw = (const float*)d_in[2];
    const float* n2  = (const float*)d_in[3];
    const float* wq  = (const float*)d_in[4];
    const float* wk  = (const float*)d_in[5];
    const float* wv  = (const float*)d_in[6];
    const float* wo  = (const float*)d_in[7];
    const float* gw  = (const float*)d_in[8];
    const float* uw  = (const float*)d_in[9];
    const float* dw  = (const float*)d_in[10];
    float* out = (float*)d_out;

    float* ws = (float*)d_ws;
    short* qbf = (short*)ws;                   // [head][4096][32] bf16
    short* kbf = (short*)(ws + 262144);        // [head][4096][32]
    short* vbf = (short*)(ws + 524288);        // [head][4096][32]
    short* obf = (short*)(ws + 786432);        // [head][4096][32]
    short* wsw = (short*)(ws + 1048576);       // 262144 shorts (wo/gw/uw/dw frags)

    k_qkv <<<256, 512, 0, stream>>>(x, n1, wq, wk, wv, wo, gw, uw, dw, wsw, qbf, kbf, vbf);
    dim3 ga(128, 4);
    k_attn<<<ga,  256, 0, stream>>>(qbf, kbf, vbf, obf);
    k_post<<<256, 512, 0, stream>>>(obf, wsw, anw, x, n2, out);
}

// Round 19
// 33.288 us; speedup vs baseline: 5.6455x; 1.0064x over previous
//
#include <hip/hip_runtime.h>
#include <hip/hip_bf16.h>

#define NVOX 4096
#define C    128
#define HID  512
#define EPSF 1e-6f

typedef __attribute__((ext_vector_type(8))) short bf16x8;
typedef __attribute__((ext_vector_type(4))) float f32x4;

__device__ __forceinline__ short f2bs(float f) {
    __hip_bfloat16 h = __float2bfloat16(f);
    short s; __builtin_memcpy(&s, &h, 2); return s;
}
__device__ __forceinline__ float bs2f(unsigned short u) {
    return __uint_as_float(((unsigned)u) << 16);
}

// A-frag from swizzled LDS tile hs[16][128] (bf16 shorts, col ^ ((row&7)<<3))
__device__ __forceinline__ bf16x8 lda(const short* hs, int lane, int ks) {
    int r = lane & 15, g = lane >> 4;
    int col = (ks * 32 + g * 8) ^ ((r & 7) << 3);
    return *(const bf16x8*)(hs + r * 128 + col);
}

__device__ __forceinline__ float wave_rsum(float s) {
    s += __shfl_xor(s, 32); s += __shfl_xor(s, 16); s += __shfl_xor(s, 8);
    s += __shfl_xor(s, 4);  s += __shfl_xor(s, 2);  s += __shfl_xor(s, 1);
    return s;
}

// ---------- K1 (512 thr, 8 waves): rmsnorm -> q,k,v head-major; qkv weights read
// directly from fp32 (no prep); folded prep of wo/gw/uw/dw for k_post ----------
__global__ __launch_bounds__(512) void k_qkv(
    const float* __restrict__ x, const float* __restrict__ n1,
    const float* __restrict__ wq, const float* __restrict__ wk,
    const float* __restrict__ wv,
    const float* __restrict__ wo, const float* __restrict__ gw,
    const float* __restrict__ uw, const float* __restrict__ dw,
    short* __restrict__ wsw,
    short* __restrict__ qbf, short* __restrict__ kbf, short* __restrict__ vbf)
{
    __shared__ short hs[2048];
    const int r0 = blockIdx.x * 16, t = threadIdx.x;
    const int w = t >> 6, lane = t & 63;
    const int g = lane >> 4, r = lane & 15;

    // folded prep: convert wo/gw/uw/dw (consumed only by k_post, 2 launches later)
    if (t < 104) {
        int gid = 6144 + blockIdx.x * 104 + t;    // [6144, 32768)
        const float* src; int base, ct, ks2, ln2, N, KS;
        if (gid < 8192)       { int loc = gid & 2047;  src = wo; base = 3 << 14; N = 128; KS = 4;
                                ct = loc >> 8; ks2 = (loc >> 6) & 3; ln2 = loc & 63; }
        else if (gid < 16384) { int loc = gid - 8192;  src = gw; base = 65536;  N = 512; KS = 4;
                                ct = loc >> 8; ks2 = (loc >> 6) & 3; ln2 = loc & 63; }
        else if (gid < 24576) { int loc = gid - 16384; src = uw; base = 131072; N = 512; KS = 4;
                                ct = loc >> 8; ks2 = (loc >> 6) & 3; ln2 = loc & 63; }
        else                  { int loc = gid - 24576; src = dw; base = 196608; N = 128; KS = 16;
                                ct = loc >> 10; ks2 = (loc >> 6) & 15; ln2 = loc & 63; }
        int k0 = ks2 * 32 + (ln2 >> 4) * 8;
        int c  = ct * 16 + (ln2 & 15);
        bf16x8 v;
        #pragma unroll
        for (int j = 0; j < 8; j++) v[j] = f2bs(src[(size_t)(k0 + j) * N + c]);
        *(bf16x8*)(wsw + base + (((ct * KS + ks2) * 64 + ln2) << 3)) = v;
    }

    // per-wave rmsnorm: wave w owns rows 2w, 2w+1
    #pragma unroll
    for (int i = 0; i < 2; i++) {
        int rr = w * 2 + i;
        const float* xp = x + (size_t)(r0 + rr) * 128;
        float v0 = xp[lane], v1 = xp[lane + 64];
        float s = wave_rsum(fmaf(v0, v0, v1 * v1));
        float sc = rsqrtf(s * (1.0f / 128.0f) + EPSF);
        int p3 = (rr & 7) << 3;
        hs[rr * 128 + (lane ^ p3)]        = f2bs(v0 * sc * n1[lane]);
        hs[rr * 128 + ((lane + 64) ^ p3)] = f2bs(v1 * sc * n1[lane + 64]);
    }
    __syncthreads();

    bf16x8 af[4];
    #pragma unroll
    for (int ks = 0; ks < 4; ks++) af[ks] = lda(hs, lane, ks);

    const int rb = g * 4;
    // 24 col-tiles over [q|k|v]; wave w does tiles 3w..3w+2
    #pragma unroll
    for (int i = 0; i < 3; i++) {
        int gt = w * 3 + i;
        int m = gt >> 3, ct = gt & 7;
        const float* srcw = (m == 0) ? wq : (m == 1) ? wk : wv;
        const float* wp = srcw + ct * 16 + r;
        f32x4 a0 = {0.f,0.f,0.f,0.f};
        #pragma unroll
        for (int ks = 0; ks < 4; ks++) {
            const float* wpk = wp + (size_t)(ks * 32 + g * 8) * 128;
            bf16x8 b0;
            #pragma unroll
            for (int j = 0; j < 8; j++) b0[j] = f2bs(wpk[(size_t)j * 128]);
            a0 = __builtin_amdgcn_mfma_f32_16x16x32_bf16(af[ks], b0, a0, 0, 0, 0);
        }
        short* outp = (m == 0) ? qbf : (m == 1) ? kbf : vbf;
        short* hp = outp + (size_t)(ct >> 1) * NVOX * 32;
        int col = (ct & 1) * 16 + r;
        #pragma unroll
        for (int j = 0; j < 4; j++)
            hp[(size_t)(r0 + rb + j) * 32 + col] = f2bs(a0[j]);
    }
}

// ---------- K2: MFMA brick attention (V-write folded into softmax phase; setprio) ----------
// LDS: [K 30720 | S2 25088 | Q 2560 | inv 128] = 58496; overlays: VB->K region, PA->S2 region
__global__ __launch_bounds__(256) void k_attn(
    const short* __restrict__ qbf, const short* __restrict__ kbf,
    const short* __restrict__ vbf, short* __restrict__ obf)
{
    __shared__ __align__(16) char smem[58496];
    short* K_lds = (short*)smem;             // [384][40] natural rows (phase 2)
    short* VB    = (short*)smem;             // V in B-frag order (phases 3a,5) — overlays K
    short* S2    = (short*)(smem + 30720);   // [32 q][392] bf16 scores (phases 2,3a)
    short* PA    = (short*)(smem + 30720);   // P in A-frag order (phases 3b,5) — overlays S2
    short* Q_lds = (short*)(smem + 55808);   // [32][40]
    float* inv   = (float*)(smem + 58368);   // [32]

    const int b = blockIdx.x, head = blockIdx.y, t = threadIdx.x;
    const int ow = (b & 3) * 4, oh = ((b >> 2) & 3) * 4, od = (b >> 4) * 2;
    const int w = t >> 6, lane = t & 63;
    const int g = lane >> 4, r = lane & 15;
    const short* kh = kbf + (size_t)head * NVOX * 32;
    const short* vh = vbf + (size_t)head * NVOX * 32;
    const short* qh = qbf + (size_t)head * NVOX * 32;
    short* oh_ = obf + (size_t)head * NVOX * 32;

    // ---- phase 1: stage K + Q; prefetch V rows into registers ----
    uint4 v0[4] = {}, v1[4] = {};
    {
        int row = t;
        int lw = row & 7, lh = (row >> 3) & 7, ld = row >> 6;
        int gd = od - 2 + ld, gh = oh - 2 + lh, gw_ = ow - 2 + lw;
        int sv = (((unsigned)gd < 16u) && ((unsigned)gh < 16u) && ((unsigned)gw_ < 16u));
        size_t off = (size_t)((((gd << 4) | gh) << 4) | gw_) * 32;
        uint4 kc[4];
        #pragma unroll
        for (int c2 = 0; c2 < 4; c2++) {
            kc[c2] = sv ? *(const uint4*)(kh + off + c2 * 8) : (uint4){0,0,0,0};
            v0[c2] = sv ? *(const uint4*)(vh + off + c2 * 8) : (uint4){0,0,0,0};
        }
        #pragma unroll
        for (int c2 = 0; c2 < 4; c2++) *(uint4*)&K_lds[row * 40 + c2 * 8] = kc[c2];

        if (t >= 128) {
            int row1 = t + 128;   // 256..383
            int lw1 = row1 & 7, lh1 = (row1 >> 3) & 7, ld1 = row1 >> 6;
            int gd1 = od - 2 + ld1, gh1 = oh - 2 + lh1, gw1 = ow - 2 + lw1;
            int sv1 = (((unsigned)gd1 < 16u) && ((unsigned)gh1 < 16u) && ((unsigned)gw1 < 16u));
            size_t off1 = (size_t)((((gd1 << 4) | gh1) << 4) | gw1) * 32;
            uint4 kd[4];
            #pragma unroll
            for (int c2 = 0; c2 < 4; c2++) {
                kd[c2] = sv1 ? *(const uint4*)(kh + off1 + c2 * 8) : (uint4){0,0,0,0};
                v1[c2] = sv1 ? *(const uint4*)(vh + off1 + c2 * 8) : (uint4){0,0,0,0};
            }
            #pragma unroll
            for (int c2 = 0; c2 < 4; c2++) *(uint4*)&K_lds[row1 * 40 + c2 * 8] = kd[c2];
        } else {
            int q = t >> 2, c2q = t & 3;
            int gq = ((od + (q >> 4)) << 8) | ((oh + ((q >> 2) & 3)) << 4) | (ow + (q & 3));
            *(uint4*)&Q_lds[q * 40 + c2q * 8] = *(const uint4*)(qh + (size_t)gq * 32 + c2q * 8);
        }
    }
    __syncthreads();

    // ---- phase 2: S[q][key] = (K · Q^T)^T — packed b64 stores ----
    {
        bf16x8 bq0 = *(const bf16x8*)(Q_lds + r * 40 + g * 8);
        bf16x8 bq1 = *(const bf16x8*)(Q_lds + (16 + r) * 40 + g * 8);
        __builtin_amdgcn_s_setprio(1);
        #pragma unroll
        for (int jj = 0; jj < 6; jj++) {
            int mt = w + jj * 4;
            bf16x8 ak = *(const bf16x8*)(K_lds + (mt * 16 + r) * 40 + g * 8);
            f32x4 a0 = {0.f,0.f,0.f,0.f}, a1 = {0.f,0.f,0.f,0.f};
            a0 = __builtin_amdgcn_mfma_f32_16x16x32_bf16(ak, bq0, a0, 0, 0, 0);
            a1 = __builtin_amdgcn_mfma_f32_16x16x32_bf16(ak, bq1, a1, 0, 0, 0);
            int key0 = mt * 16 + g * 4;
            short s4[4];
            #pragma unroll
            for (int i = 0; i < 4; i++) s4[i] = f2bs(a0[i]);
            unsigned long long pk0; __builtin_memcpy(&pk0, s4, 8);
            *(unsigned long long*)&S2[r * 392 + key0] = pk0;
            #pragma unroll
            for (int i = 0; i < 4; i++) s4[i] = f2bs(a1[i]);
            unsigned long long pk1; __builtin_memcpy(&pk1, s4, 8);
            *(unsigned long long*)&S2[(16 + r) * 392 + key0] = pk1;
        }
        __builtin_amdgcn_s_setprio(0);
    }
    __syncthreads();

    // ---- phase 3a: load S rows to regs; write V (regs) into VB (overlays dead K) ----
    const int q = t >> 3, kl = t & 7;
    uint4 sraw[6];
    #pragma unroll
    for (int jj = 0; jj < 6; jj++)
        sraw[jj] = *(const uint4*)&S2[q * 392 + kl * 48 + jj * 8];
    {
        int row = t;
        int ks = row >> 5, g3 = (row >> 3) & 3, j3 = row & 7;
        const unsigned short* u = (const unsigned short*)v0;
        #pragma unroll
        for (int c = 0; c < 32; c++)
            VB[((c >> 4) * 12 + ks) * 512 + g3 * 128 + (c & 15) * 8 + j3] = (short)u[c];
        if (t >= 128) {
            int row1 = t + 128;
            int ks1 = row1 >> 5, g31 = (row1 >> 3) & 3, j31 = row1 & 7;
            const unsigned short* u1 = (const unsigned short*)v1;
            #pragma unroll
            for (int c = 0; c < 32; c++)
                VB[((c >> 4) * 12 + ks1) * 512 + g31 * 128 + (c & 15) * 8 + j31] = (short)u1[c];
        }
    }
    __syncthreads();   // all S reads done (PA overlays S2) + VB ready

    // ---- phase 3b: masked softmax from registers; write P in A-frag order ----
    {
        const int qw_ = q & 3, qh_ = (q >> 2) & 3, qd_ = q >> 4;
        const float isq = 0.17677669529663687f;   // 1/sqrt(32)
        unsigned long long okb = 0;
        float mx = -1e30f;
        #pragma unroll
        for (int jj = 0; jj < 6; jj++) {
            const unsigned short* u = (const unsigned short*)&sraw[jj];
            #pragma unroll
            for (int e = 0; e < 8; e++) {
                int k = kl * 48 + jj * 8 + e;
                int lw = k & 7, lh = (k >> 3) & 7, ld = k >> 6;
                int ok = ((unsigned)(ld - qd_) <= 4u) & ((unsigned)(lh - qh_) <= 4u)
                       & ((unsigned)(lw - qw_) <= 4u)
                       & ((unsigned)(od - 2 + ld) < 16u) & ((unsigned)(oh - 2 + lh) < 16u)
                       & ((unsigned)(ow - 2 + lw) < 16u);
                float s = bs2f(u[e]) * isq;
                mx = ok ? fmaxf(mx, s) : mx;
                okb |= ((unsigned long long)ok) << (jj * 8 + e);
            }
        }
        mx = fmaxf(mx, __shfl_xor(mx, 1));
        mx = fmaxf(mx, __shfl_xor(mx, 2));
        mx = fmaxf(mx, __shfl_xor(mx, 4));
        float ssum = 0.f;
        #pragma unroll
        for (int jj = 0; jj < 6; jj++) {
            const unsigned short* u = (const unsigned short*)&sraw[jj];
            #pragma unroll
            for (int e = 0; e < 8; e++) {
                int k = kl * 48 + jj * 8 + e;
                float s = bs2f(u[e]) * isq;
                float p = ((okb >> (jj * 8 + e)) & 1) ? __expf(s - mx) : 0.f;
                ssum += p;
                PA[((q >> 4) * 12 + (k >> 5)) * 512 + ((k >> 3) & 3) * 128 + (q & 15) * 8 + (k & 7)] = f2bs(p);
            }
        }
        ssum += __shfl_xor(ssum, 1);
        ssum += __shfl_xor(ssum, 2);
        ssum += __shfl_xor(ssum, 4);
        if (kl == 0) inv[q] = 1.0f / ssum;
    }
    __syncthreads();

    // ---- phase 5: O[q][c] = P · V  (head-major output) ----
    {
        const int mt2 = w >> 1, ct = w & 1;
        f32x4 acc = {0.f,0.f,0.f,0.f};
        __builtin_amdgcn_s_setprio(1);
        #pragma unroll
        for (int ks = 0; ks < 12; ks++) {
            bf16x8 pa = *(const bf16x8*)(PA + (((mt2 * 12 + ks) * 64 + lane) << 3));
            bf16x8 vb = *(const bf16x8*)(VB + (((ct * 12 + ks) * 64 + lane) << 3));
            acc = __builtin_amdgcn_mfma_f32_16x16x32_bf16(pa, vb, acc, 0, 0, 0);
        }
        __builtin_amdgcn_s_setprio(0);
        #pragma unroll
        for (int i = 0; i < 4; i++) {
            int qq = mt2 * 16 + g * 4 + i;
            int c = ct * 16 + r;
            int gvox = ((od + (qq >> 4)) << 8) | ((oh + ((qq >> 2) & 3)) << 4) | (ow + (qq & 3));
            oh_[(size_t)gvox * 32 + c] = f2bs(acc[i] * inv[qq]);
        }
    }
}

// ---------- K3 (512 thr, 8 waves): fused post-chain ----------
__global__ __launch_bounds__(512) void k_post(
    const short* __restrict__ obf, const short* __restrict__ wsw,
    const float* __restrict__ anw, const float* __restrict__ x,
    const float* __restrict__ n2w, float* __restrict__ out)
{
    __shared__ float ybuf[16][132];
    __shared__ float xres[16][128];
    __shared__ short hs[2048];
    __shared__ short gu[16 * 512];

    const int r0 = blockIdx.x * 16, t = threadIdx.x;
    const int w = t >> 6, lane = t & 63;
    const int ar = lane & 15, ag_ = lane >> 4;

    // phase 1: y = o @ wo  (8 waves x one 16-col tile; obf head-major: head = ks)
    {
        const short* wb = wsw + (3 << 14);
        f32x4 a0 = {0.f,0.f,0.f,0.f};
        #pragma unroll
        for (int ks = 0; ks < 4; ks++) {
            bf16x8 a = *(const bf16x8*)(obf + (size_t)ks * NVOX * 32 + (size_t)(r0 + ar) * 32 + ag_ * 8);
            bf16x8 b0 = *(const bf16x8*)(wb + (((w * 4 + ks) * 64 + lane) << 3));
            a0 = __builtin_amdgcn_mfma_f32_16x16x32_bf16(a, b0, a0, 0, 0, 0);
        }
        #pragma unroll
        for (int i = 0; i < 4; i++)
            ybuf[ag_ * 4 + i][w * 16 + ar] = a0[i];
    }
    __syncthreads();

    // phase 2+3 fused, per-wave: wave w owns rows 2w, 2w+1
    #pragma unroll
    for (int i = 0; i < 2; i++) {
        int r = w * 2 + i;
        float y0 = ybuf[r][lane], y1 = ybuf[r][lane + 64];
        float s = wave_rsum(fmaf(y0, y0, y1 * y1));
        float sc = rsqrtf(s * (1.0f / 128.0f) + EPSF);
        const float* xp = x + (size_t)(r0 + r) * 128;
        float xr0 = xp[lane]      + y0 * sc * anw[lane];
        float xr1 = xp[lane + 64] + y1 * sc * anw[lane + 64];
        xres[r][lane] = xr0; xres[r][lane + 64] = xr1;
        float s2 = wave_rsum(fmaf(xr0, xr0, xr1 * xr1));
        float sc2 = rsqrtf(s2 * (1.0f / 128.0f) + EPSF);
        int p3 = (r & 7) << 3;
        hs[r * 128 + (lane ^ p3)]        = f2bs(xr0 * sc2 * n2w[lane]);
        hs[r * 128 + ((lane + 64) ^ p3)] = f2bs(xr1 * sc2 * n2w[lane + 64]);
    }
    __syncthreads();

    // phase 4: gu = silu(h2@gw)*(h2@uw)  (8 waves x 4 col-tiles)
    {
        const short* gwb = wsw + 65536;
        const short* uwb = wsw + 131072;
        bf16x8 af[4];
        #pragma unroll
        for (int ks = 0; ks < 4; ks++) af[ks] = lda(hs, lane, ks);
        f32x4 ag[4], au[4];
        #pragma unroll
        for (int i = 0; i < 4; i++) { ag[i] = (f32x4){0.f,0.f,0.f,0.f}; au[i] = (f32x4){0.f,0.f,0.f,0.f}; }
        #pragma unroll
        for (int ks = 0; ks < 4; ks++) {
            #pragma unroll
            for (int i = 0; i < 4; i++) {
                int ct = w * 4 + i;
                bf16x8 bg = *(const bf16x8*)(gwb + (((ct * 4 + ks) * 64 + lane) << 3));
                bf16x8 bu = *(const bf16x8*)(uwb + (((ct * 4 + ks) * 64 + lane) << 3));
                ag[i] = __builtin_amdgcn_mfma_f32_16x16x32_bf16(af[ks], bg, ag[i], 0, 0, 0);
                au[i] = __builtin_amdgcn_mfma_f32_16x16x32_bf16(af[ks], bu, au[i], 0, 0, 0);
            }
        }
        #pragma unroll
        for (int i = 0; i < 4; i++) {
            int col = (w * 4 + i) * 16 + ar;
            #pragma unroll
            for (int j = 0; j < 4; j++) {
                int row = ag_ * 4 + j;
                float g = ag[i][j], uu = au[i][j];
                float sg = g / (1.0f + __expf(-g));
                gu[row * 512 + (col ^ ((row & 7) << 3))] = f2bs(sg * uu);
            }
        }
    }
    __syncthreads();

    // phase 5: out = xres + gu @ dw  (8 waves x one 16-col tile, K=512)
    {
        const short* db = wsw + 196608;
        f32x4 a0 = {0.f,0.f,0.f,0.f};
        #pragma unroll
        for (int ks = 0; ks < 16; ks++) {
            int col = (ks * 32 + ag_ * 8) ^ ((ar & 7) << 3);
            bf16x8 a = *(const bf16x8*)(gu + ar * 512 + col);
            bf16x8 b0 = *(const bf16x8*)(db + (((w * 16 + ks) * 64 + lane) << 3));
            a0 = __builtin_amdgcn_mfma_f32_16x16x32_bf16(a, b0, a0, 0, 0, 0);
        }
        #pragma unroll
        for (int i = 0; i < 4; i++) {
            int row = ag_ * 4 + i;
            size_t i0 = (size_t)(r0 + row) * 128 + w * 16 + ar;
            out[i0] = xres[row][w * 16 + ar] + a0[i];
        }
    }
}

extern "C" void kernel_launch(void* const* d_in, const int* in_sizes, int n_in,
                              void* d_out, int out_size, void* d_ws, size_t ws_size,
                              hipStream_t stream)
{
    const float* x   = (const float*)d_in[0];
    const float* n1  = (const float*)d_in[1];
    const float* anw = (const float*)d_in[2];
    const float* n2  = (const float*)d_in[3];
    const float* wq  = (const float*)d_in[4];
    const float* wk  = (const float*)d_in[5];
    const float* wv  = (const float*)d_in[6];
    const float* wo  = (const float*)d_in[7];
    const float* gw  = (const float*)d_in[8];
    const float* uw  = (const float*)d_in[9];
    const float* dw  = (const float*)d_in[10];
    float* out = (float*)d_out;

    float* ws = (float*)d_ws;
    short* qbf = (short*)ws;                   // [head][4096][32] bf16
    short* kbf = (short*)(ws + 262144);        // [head][4096][32]
    short* vbf = (short*)(ws + 524288);        // [head][4096][32]
    short* obf = (short*)(ws + 786432);        // [head][4096][32]
    short* wsw = (short*)(ws + 1048576);       // 262144 shorts (wo/gw/uw/dw frags)

    k_qkv <<<256, 512, 0, stream>>>(x, n1, wq, wk, wv, wo, gw, uw, dw, wsw, qbf, kbf, vbf);
    dim3 ga(128, 4);
    k_attn<<<ga,  256, 0, stream>>>(qbf, kbf, vbf, obf);
    k_post<<<256, 512, 0, stream>>>(obf, wsw, anw, x, n2, out);
}